// Round 3
// baseline (1063.772 us; speedup 1.0000x reference)
//
#include <hip/hip_runtime.h>
#include <math.h>

#define D 128

typedef short bf16x8 __attribute__((ext_vector_type(8)));
typedef float f32x4 __attribute__((ext_vector_type(4)));
typedef float f4 __attribute__((ext_vector_type(4)));
typedef unsigned short u16x4 __attribute__((ext_vector_type(4)));

__device__ __forceinline__ unsigned short f2bf(float f) {
    unsigned int u = __float_as_uint(f);
    u += 0x7fff + ((u >> 16) & 1);   // round-to-nearest-even
    return (unsigned short)(u >> 16);
}
__device__ __forceinline__ float bf2f(unsigned short h) {
    return __uint_as_float(((unsigned int)h) << 16);
}
__device__ __forceinline__ bf16x8 load_bf8(const unsigned short* p) {
    return __builtin_bit_cast(bf16x8, *reinterpret_cast<const uint4*>(p));
}

// x[n][d] = emb[z[n]][d]; also emit bf16 hi/lo split. float4 per thread.
__global__ __launch_bounds__(256) void k_embed(const int* __restrict__ z,
        const float* __restrict__ emb, float* __restrict__ x,
        unsigned short* __restrict__ xh, unsigned short* __restrict__ xl, int N) {
    int idx = blockIdx.x * blockDim.x + threadIdx.x;       // N*32 threads
    if (idx >= N * 32) return;
    int n = idx >> 5;
    int d0 = (idx & 31) * 4;
    f4 v = *reinterpret_cast<const f4*>(emb + (size_t)z[n] * D + d0);
    *reinterpret_cast<f4*>(x + (size_t)n * D + d0) = v;
    u16x4 h, l;
    #pragma unroll
    for (int c = 0; c < 4; c++) {
        h[c] = f2bf(v[c]);
        l[c] = f2bf(v[c] - bf2f(h[c]));
    }
    *reinterpret_cast<u16x4*>(xh + (size_t)n * D + d0) = h;
    *reinterpret_cast<u16x4*>(xl + (size_t)n * D + d0) = l;
}

__global__ void k_dist(const int* __restrict__ row, const int* __restrict__ col,
                       const float* __restrict__ pos, float* __restrict__ dist, int E) {
    int e = blockIdx.x * blockDim.x + threadIdx.x;
    if (e >= E) return;
    int r = row[e], c = col[e];
    float dx = pos[3 * r + 0] - pos[3 * c + 0];
    float dy = pos[3 * r + 1] - pos[3 * c + 1];
    float dz = pos[3 * r + 2] - pos[3 * c + 2];
    dist[e] = sqrtf(dx * dx + dy * dy + dz * dz);
}

// Pre-transpose + bf16 hi/lo split all layer weights (tiny, once).
__global__ void k_cvtW(const float* __restrict__ Wf, const float* __restrict__ Ws,
                       unsigned short* __restrict__ Wth, unsigned short* __restrict__ Wtl,
                       int L) {
    int idx = blockIdx.x * blockDim.x + threadIdx.x;
    if (idx >= L * 4 * D * D) return;
    int k = idx & 127;
    int n = (idx >> 7) & 127;
    int mat = (idx >> 14) & 3;
    int l = idx >> 16;
    const float* src = (mat < 2) ? Wf : Ws;
    float v = src[(size_t)l * 257 * D + (size_t)((mat & 1) * D + k) * D + n];
    unsigned short h = f2bf(v);
    Wth[idx] = h;
    Wtl[idx] = f2bf(v - bf2f(h));
}

// Split-bf16 MFMA GEMM. Outputs interleaved: AfAs[N][256] = [Af|As], BfBs[N][256] = [Bf|Bs]
__global__ __launch_bounds__(256) void k_gemm_mfma(
        const unsigned short* __restrict__ Xh, const unsigned short* __restrict__ Xl,
        const unsigned short* __restrict__ Wth, const unsigned short* __restrict__ Wtl,
        const float* __restrict__ bfl, const float* __restrict__ bsl,
        float* __restrict__ AfAs, float* __restrict__ BfBs) {
    int mat = blockIdx.y;                      // 0=Af 1=Bf 2=As 3=Bs
    float* O = ((mat & 1) ? BfBs : AfAs) + ((mat >> 1) ? 128 : 0);
    const float* bias = (mat == 0) ? bfl : (mat == 2) ? bsl : nullptr;
    const unsigned short* Wh = Wth + (size_t)mat * D * D;
    const unsigned short* Wl = Wtl + (size_t)mat * D * D;

    int wave = threadIdx.x >> 6;
    int lane = threadIdx.x & 63;
    int r16 = lane & 15;
    int kg = lane >> 4;
    int row0 = blockIdx.x * 128 + (wave >> 1) * 64;
    int wc = (wave & 1) * 64;

    f32x4 acc[4][4];
    #pragma unroll
    for (int m = 0; m < 4; m++)
        #pragma unroll
        for (int n = 0; n < 4; n++) acc[m][n] = (f32x4){0.f, 0.f, 0.f, 0.f};

    #pragma unroll
    for (int ks = 0; ks < 4; ++ks) {
        int k0 = ks * 32 + kg * 8;
        bf16x8 ah[4], al[4], bh[4], bl[4];
        #pragma unroll
        for (int m = 0; m < 4; m++) {
            size_t off = (size_t)(row0 + m * 16 + r16) * D + k0;
            ah[m] = load_bf8(Xh + off);
            al[m] = load_bf8(Xl + off);
        }
        #pragma unroll
        for (int n = 0; n < 4; n++) {
            size_t off = (size_t)(wc + n * 16 + r16) * D + k0;
            bh[n] = load_bf8(Wh + off);
            bl[n] = load_bf8(Wl + off);
        }
        #pragma unroll
        for (int m = 0; m < 4; m++)
            #pragma unroll
            for (int n = 0; n < 4; n++) {
                acc[m][n] = __builtin_amdgcn_mfma_f32_16x16x32_bf16(ah[m], bh[n], acc[m][n], 0, 0, 0);
                acc[m][n] = __builtin_amdgcn_mfma_f32_16x16x32_bf16(al[m], bh[n], acc[m][n], 0, 0, 0);
                acc[m][n] = __builtin_amdgcn_mfma_f32_16x16x32_bf16(ah[m], bl[n], acc[m][n], 0, 0, 0);
            }
    }

    // C/D layout: col = lane&15, row = (lane>>4)*4 + reg
    #pragma unroll
    for (int n = 0; n < 4; n++) {
        int col = wc + n * 16 + r16;
        float bv = bias ? bias[col] : 0.0f;
        #pragma unroll
        for (int m = 0; m < 4; m++) {
            int rbase = row0 + m * 16 + kg * 4;
            #pragma unroll
            for (int r = 0; r < 4; r++)
                O[(size_t)(rbase + r) * 256 + col] = acc[m][n][r] + bv;
        }
    }
}

// Edge gate + aggregate. 32 lanes per node, float4 per lane, shfl-broadcast (j,dist).
__global__ __launch_bounds__(256) void k_edges(
        const int* __restrict__ row, const float* __restrict__ dist,
        const float* __restrict__ AfAs, const float* __restrict__ BfBs,
        const float* __restrict__ wfd, const float* __restrict__ wsd,
        float* __restrict__ agg, int N, int deg) {
    int grp = threadIdx.x >> 5;
    int lane = threadIdx.x & 31;
    int node = blockIdx.x * 8 + grp;
    if (node >= N) return;
    int d0 = lane * 4;
    const f4 af4 = *reinterpret_cast<const f4*>(AfAs + (size_t)node * 256 + d0);
    const f4 as4 = *reinterpret_cast<const f4*>(AfAs + (size_t)node * 256 + 128 + d0);
    const f4 wf4 = *reinterpret_cast<const f4*>(wfd + d0);
    const f4 ws4 = *reinterpret_cast<const f4*>(wsd + d0);
    size_t base = (size_t)node * deg;
    int jme = (lane < deg) ? row[base + lane] : 0;
    float dme = (lane < deg) ? dist[base + lane] : 0.0f;
    f4 acc = {0.f, 0.f, 0.f, 0.f};
    #pragma unroll 4
    for (int e = 0; e < deg; e++) {
        int j = __shfl(jme, e, 32);
        float dst = __shfl(dme, e, 32);
        const f4* bp = reinterpret_cast<const f4*>(BfBs + (size_t)j * 256 + d0);
        f4 bf4 = bp[0];
        f4 bs4 = bp[32];          // +128 floats, same base reg, imm offset
        #pragma unroll
        for (int c = 0; c < 4; c++) {
            float u  = fmaf(dst, wf4[c], af4[c]) + bf4[c];
            float vv = fmaf(dst, ws4[c], as4[c]) + bs4[c];
            float sg = __builtin_amdgcn_rcpf(1.0f + __expf(-u));
            float sp = fmaxf(vv, 0.0f) + __logf(1.0f + __expf(-fabsf(vv)));
            acc[c] = fmaf(sg, sp, acc[c]);
        }
    }
    *reinterpret_cast<f4*>(agg + (size_t)node * D + d0) = acc;
}

// per-feature sum/sumsq of P[N][D] -> atomicAdd (pre-zeroed). float4 per thread.
__global__ __launch_bounds__(256) void k_stats(const float* __restrict__ P,
        float* __restrict__ sums, float* __restrict__ sumsq, int N) {
    __shared__ f4 s1[256], s2[256];
    int tid = threadIdx.x;
    int sl = tid & 31, grp = tid >> 5;
    int d0 = sl * 4;
    f4 a = {0.f, 0.f, 0.f, 0.f}, b = {0.f, 0.f, 0.f, 0.f};
    for (int r = blockIdx.x * 8 + grp; r < N; r += gridDim.x * 8) {
        f4 v = *reinterpret_cast<const f4*>(P + (size_t)r * D + d0);
        a += v;
        b += v * v;
    }
    s1[tid] = a;
    s2[tid] = b;
    __syncthreads();
    if (tid < 64) {
        int which = tid >> 5, l = tid & 31;
        f4 acc = which ? s2[l] : s1[l];
        #pragma unroll
        for (int g = 1; g < 8; g++) acc += which ? s2[g * 32 + l] : s1[g * 32 + l];
        float* dstp = which ? sumsq : sums;
        #pragma unroll
        for (int c = 0; c < 4; c++) atomicAdd(dstp + l * 4 + c, acc[c]);
    }
}

// xnew = gc*(agg-mu1)*rsqrt(var1+eps)+bc+x (in place), accumulate stats of xnew.
__global__ __launch_bounds__(256) void k_bn1res(
        const float* __restrict__ sums1, const float* __restrict__ sumsq1,
        const float* __restrict__ gc, const float* __restrict__ bc,
        const float* __restrict__ x, float* __restrict__ aggxnew,
        float* __restrict__ sums2, float* __restrict__ sumsq2, int N) {
    __shared__ f4 s1[256], s2[256];
    int tid = threadIdx.x;
    int sl = tid & 31, grp = tid >> 5;
    int d0 = sl * 4;
    float invN = 1.0f / (float)N;
    f4 mu = *reinterpret_cast<const f4*>(sums1 + d0);
    f4 sq = *reinterpret_cast<const f4*>(sumsq1 + d0);
    f4 g4 = *reinterpret_cast<const f4*>(gc + d0);
    f4 b4 = *reinterpret_cast<const f4*>(bc + d0);
    f4 inv;
    #pragma unroll
    for (int c = 0; c < 4; c++) {
        float m = mu[c] * invN;
        mu[c] = m;
        inv[c] = rsqrtf(sq[c] * invN - m * m + 1e-5f);
    }
    f4 sa = {0.f, 0.f, 0.f, 0.f}, sb = {0.f, 0.f, 0.f, 0.f};
    for (int r = blockIdx.x * 8 + grp; r < N; r += gridDim.x * 8) {
        size_t idx = (size_t)r * D + d0;
        f4 v = *reinterpret_cast<const f4*>(aggxnew + idx);
        f4 xv = *reinterpret_cast<const f4*>(x + idx);
        f4 xn;
        #pragma unroll
        for (int c = 0; c < 4; c++) xn[c] = fmaf(g4[c] * (v[c] - mu[c]), inv[c], b4[c]) + xv[c];
        *reinterpret_cast<f4*>(aggxnew + idx) = xn;
        sa += xn;
        sb += xn * xn;
    }
    s1[tid] = sa;
    s2[tid] = sb;
    __syncthreads();
    if (tid < 64) {
        int which = tid >> 5, l = tid & 31;
        f4 acc = which ? s2[l] : s1[l];
        #pragma unroll
        for (int g = 1; g < 8; g++) acc += which ? s2[g * 32 + l] : s1[g * 32 + l];
        float* dstp = which ? sumsq2 : sums2;
        #pragma unroll
        for (int c = 0; c < 4; c++) atomicAdd(dstp + l * 4 + c, acc[c]);
    }
}

// x = relu(gn*(xnew-mu2)*rsqrt(var2+eps)+bnb); emit bf16 hi/lo. float4 per thread.
__global__ __launch_bounds__(256) void k_bn2relu(
        const float* __restrict__ sums2, const float* __restrict__ sumsq2,
        const float* __restrict__ gn, const float* __restrict__ bnb,
        const float* __restrict__ xnew, float* __restrict__ xout,
        unsigned short* __restrict__ xh, unsigned short* __restrict__ xl, int N) {
    int idx = blockIdx.x * blockDim.x + threadIdx.x;      // N*32 threads
    if (idx >= N * 32) return;
    int n = idx >> 5;
    int d0 = (idx & 31) * 4;
    float invN = 1.0f / (float)N;
    f4 mu = *reinterpret_cast<const f4*>(sums2 + d0);
    f4 sq = *reinterpret_cast<const f4*>(sumsq2 + d0);
    f4 g4 = *reinterpret_cast<const f4*>(gn + d0);
    f4 b4 = *reinterpret_cast<const f4*>(bnb + d0);
    f4 v = *reinterpret_cast<const f4*>(xnew + (size_t)n * D + d0);
    f4 o;
    u16x4 h, l;
    #pragma unroll
    for (int c = 0; c < 4; c++) {
        float m = mu[c] * invN;
        float inv = rsqrtf(sq[c] * invN - m * m + 1e-5f);
        float t = fmaf(g4[c] * (v[c] - m), inv, b4[c]);
        t = fmaxf(t, 0.0f);
        o[c] = t;
        h[c] = f2bf(t);
        l[c] = f2bf(t - bf2f(h[c]));
    }
    *reinterpret_cast<f4*>(xout + (size_t)n * D + d0) = o;
    *reinterpret_cast<u16x4*>(xh + (size_t)n * D + d0) = h;
    *reinterpret_cast<u16x4*>(xl + (size_t)n * D + d0) = l;
}

// global mean pool per graph + relu(g@W1+b1) @ W2 + b2
__global__ __launch_bounds__(256) void k_head(const float* __restrict__ x,
        const float* __restrict__ W1, const float* __restrict__ b1,
        const float* __restrict__ W2, const float* __restrict__ b2,
        float* __restrict__ out, int S) {
    __shared__ float gmean[D];
    __shared__ float red[256];
    int g = blockIdx.x;
    int d = threadIdx.x & 127;
    int half = threadIdx.x >> 7;
    float s = 0.0f;
    size_t rbase = (size_t)g * S;
    for (int r = half; r < S; r += 2) s += x[(rbase + r) * D + d];
    red[threadIdx.x] = s;
    __syncthreads();
    if (threadIdx.x < 128) gmean[d] = (red[threadIdx.x] + red[threadIdx.x + 128]) / (float)S;
    __syncthreads();
    float val = 0.0f;
    if (threadIdx.x < 128) {
        float h = b1[d];
        #pragma unroll 8
        for (int k = 0; k < D; k++) h = fmaf(gmean[k], W1[k * D + d], h);
        h = fmaxf(h, 0.0f);
        val = h * W2[d];
    }
    red[threadIdx.x] = val;
    __syncthreads();
    for (int st = 128; st > 0; st >>= 1) {
        if (threadIdx.x < st) red[threadIdx.x] += red[threadIdx.x + st];
        __syncthreads();
    }
    if (threadIdx.x == 0) out[g] = red[0] + b2[0];
}

extern "C" void kernel_launch(void* const* d_in, const int* in_sizes, int n_in,
                              void* d_out, int out_size, void* d_ws, size_t ws_size,
                              hipStream_t stream) {
    const int*   z    = (const int*)d_in[0];
    const float* pos  = (const float*)d_in[1];
    const int*   eidx = (const int*)d_in[3];
    const float* emb  = (const float*)d_in[4];
    const float* Wf   = (const float*)d_in[5];
    const float* bf   = (const float*)d_in[6];
    const float* Ws   = (const float*)d_in[7];
    const float* bs   = (const float*)d_in[8];
    const float* gc   = (const float*)d_in[9];
    const float* bc   = (const float*)d_in[10];
    const float* gn   = (const float*)d_in[11];
    const float* bnb  = (const float*)d_in[12];
    const float* W1   = (const float*)d_in[13];
    const float* b1   = (const float*)d_in[14];
    const float* W2   = (const float*)d_in[15];
    const float* b2   = (const float*)d_in[16];

    int N = in_sizes[0];
    int E = in_sizes[3] / 2;
    int L = in_sizes[6] / D;
    int deg = E / N;
    int S = N / out_size;

    const int* row = eidx;
    const int* col = eidx + E;

    float* ws = (float*)d_ws;
    size_t nd = (size_t)N * D;
    float* x    = ws;                  // [N][128]
    float* AfAs = x + nd;              // [N][256]
    float* BfBs = AfAs + 2 * nd;       // [N][256]
    float* agg  = BfBs + 2 * nd;       // [N][128], reused as xnew in place
    float* dist = agg + nd;            // [E]
    unsigned short* xh  = (unsigned short*)(dist + E);
    unsigned short* xl  = xh + nd;
    unsigned short* Wth = xl + nd;                          // L*4*128*128 bf16
    unsigned short* Wtl = Wth + (size_t)L * 4 * D * D;
    float* stats = (float*)(Wtl + (size_t)L * 4 * D * D);   // L*512 floats

    hipMemsetAsync(stats, 0, (size_t)L * 512 * sizeof(float), stream);

    k_cvtW<<<(L * 4 * D * D + 255) / 256, 256, 0, stream>>>(Wf, Ws, Wth, Wtl, L);
    k_embed<<<(N * 32 + 255) / 256, 256, 0, stream>>>(z, emb, x, xh, xl, N);
    k_dist<<<(E + 255) / 256, 256, 0, stream>>>(row, col, pos, dist, E);

    for (int l = 0; l < L; ++l) {
        const float* Wfl = Wf + (size_t)l * 257 * D;
        const float* Wsl = Ws + (size_t)l * 257 * D;
        float* st = stats + (size_t)l * 512;
        k_gemm_mfma<<<dim3(N / 128, 4), 256, 0, stream>>>(
            xh, xl, Wth + (size_t)l * 4 * D * D, Wtl + (size_t)l * 4 * D * D,
            bf + l * D, bs + l * D, AfAs, BfBs);
        k_edges<<<(N + 7) / 8, 256, 0, stream>>>(row, dist, AfAs, BfBs,
                                                 Wfl + 256 * D, Wsl + 256 * D, agg, N, deg);
        k_stats<<<256, 256, 0, stream>>>(agg, st, st + 128, N);
        k_bn1res<<<256, 256, 0, stream>>>(st, st + 128, gc + l * D, bc + l * D,
                                          x, agg, st + 256, st + 384, N);
        k_bn2relu<<<(N * 32 + 255) / 256, 256, 0, stream>>>(st + 256, st + 384,
                                                            gn + l * D, bnb + l * D, agg, x, xh, xl, N);
    }
    k_head<<<out_size, 256, 0, stream>>>(x, W1, b1, W2, b2, (float*)d_out, S);
}

// Round 4
// 873.054 us; speedup vs baseline: 1.2184x; 1.2184x over previous
//
#include <hip/hip_runtime.h>
#include <math.h>

#define D 128

typedef short bf16x8 __attribute__((ext_vector_type(8)));
typedef float f32x4 __attribute__((ext_vector_type(4)));
typedef float f4 __attribute__((ext_vector_type(4)));
typedef unsigned short u16x4 __attribute__((ext_vector_type(4)));

__device__ __forceinline__ unsigned short f2bf(float f) {
    unsigned int u = __float_as_uint(f);
    u += 0x7fff + ((u >> 16) & 1);   // round-to-nearest-even
    return (unsigned short)(u >> 16);
}
__device__ __forceinline__ float bf2f(unsigned short h) {
    return __uint_as_float(((unsigned int)h) << 16);
}
__device__ __forceinline__ bf16x8 load_bf8(const unsigned short* p) {
    return __builtin_bit_cast(bf16x8, *reinterpret_cast<const uint4*>(p));
}

// x[n][d] = emb[z[n]][d]; also emit bf16 hi/lo split. float4 per thread.
__global__ __launch_bounds__(256) void k_embed(const int* __restrict__ z,
        const float* __restrict__ emb, float* __restrict__ x,
        unsigned short* __restrict__ xh, unsigned short* __restrict__ xl, int N) {
    int idx = blockIdx.x * blockDim.x + threadIdx.x;       // N*32 threads
    if (idx >= N * 32) return;
    int n = idx >> 5;
    int d0 = (idx & 31) * 4;
    f4 v = *reinterpret_cast<const f4*>(emb + (size_t)z[n] * D + d0);
    *reinterpret_cast<f4*>(x + (size_t)n * D + d0) = v;
    u16x4 h, l;
    #pragma unroll
    for (int c = 0; c < 4; c++) {
        h[c] = f2bf(v[c]);
        l[c] = f2bf(v[c] - bf2f(h[c]));
    }
    *reinterpret_cast<u16x4*>(xh + (size_t)n * D + d0) = h;
    *reinterpret_cast<u16x4*>(xl + (size_t)n * D + d0) = l;
}

// jd[e] = (row[e], bits(||pos[row]-pos[col]||)) packed
__global__ void k_dist(const int* __restrict__ row, const int* __restrict__ col,
                       const float* __restrict__ pos, int2* __restrict__ jd, int E) {
    int e = blockIdx.x * blockDim.x + threadIdx.x;
    if (e >= E) return;
    int r = row[e], c = col[e];
    float dx = pos[3 * r + 0] - pos[3 * c + 0];
    float dy = pos[3 * r + 1] - pos[3 * c + 1];
    float dz = pos[3 * r + 2] - pos[3 * c + 2];
    float dist = sqrtf(dx * dx + dy * dy + dz * dz);
    jd[e] = make_int2(r, __float_as_int(dist));
}

// Pre-transpose + bf16 hi/lo split all layer weights (tiny, once).
__global__ void k_cvtW(const float* __restrict__ Wf, const float* __restrict__ Ws,
                       unsigned short* __restrict__ Wth, unsigned short* __restrict__ Wtl,
                       int L) {
    int idx = blockIdx.x * blockDim.x + threadIdx.x;
    if (idx >= L * 4 * D * D) return;
    int k = idx & 127;
    int n = (idx >> 7) & 127;
    int mat = (idx >> 14) & 3;
    int l = idx >> 16;
    const float* src = (mat < 2) ? Wf : Ws;
    float v = src[(size_t)l * 257 * D + (size_t)((mat & 1) * D + k) * D + n];
    unsigned short h = f2bf(v);
    Wth[idx] = h;
    Wtl[idx] = f2bf(v - bf2f(h));
}

// Split-bf16 MFMA GEMM, graph-affine XCD swizzle on row tiles.
// Outputs interleaved: AfAs[N][256] = [Af|As], BfBs[N][256] = [Bf|Bs]
__global__ __launch_bounds__(256) void k_gemm_mfma(
        const unsigned short* __restrict__ Xh, const unsigned short* __restrict__ Xl,
        const unsigned short* __restrict__ Wth, const unsigned short* __restrict__ Wtl,
        const float* __restrict__ bfl, const float* __restrict__ bsl,
        float* __restrict__ AfAs, float* __restrict__ BfBs, int S, int G) {
    int mat = blockIdx.y;                      // 0=Af 1=Bf 2=As 3=Bs
    float* O = ((mat & 1) ? BfBs : AfAs) + ((mat >> 1) ? 128 : 0);
    const float* bias = (mat == 0) ? bfl : (mat == 2) ? bsl : nullptr;
    const unsigned short* Wh = Wth + (size_t)mat * D * D;
    const unsigned short* Wl = Wtl + (size_t)mat * D * D;

    int wave = threadIdx.x >> 6;
    int lane = threadIdx.x & 63;
    int r16 = lane & 15;
    int kg = lane >> 4;

    int xb = blockIdx.x;
    int tile0;
    if ((G & 7) == 0 && (S & 127) == 0) {
        int xcd = xb & 7, i = xb >> 3;
        int tpg = S >> 7;                       // 128-row tiles per graph
        int gi = i / tpg, t = i - gi * tpg;
        tile0 = (xcd + 8 * gi) * S + t * 128;   // graph g on XCD g%8
    } else tile0 = xb * 128;
    int row0 = tile0 + (wave >> 1) * 64;
    int wc = (wave & 1) * 64;

    f32x4 acc[4][4];
    #pragma unroll
    for (int m = 0; m < 4; m++)
        #pragma unroll
        for (int n = 0; n < 4; n++) acc[m][n] = (f32x4){0.f, 0.f, 0.f, 0.f};

    #pragma unroll
    for (int ks = 0; ks < 4; ++ks) {
        int k0 = ks * 32 + kg * 8;
        bf16x8 ah[4], al[4], bh[4], bl[4];
        #pragma unroll
        for (int m = 0; m < 4; m++) {
            size_t off = (size_t)(row0 + m * 16 + r16) * D + k0;
            ah[m] = load_bf8(Xh + off);
            al[m] = load_bf8(Xl + off);
        }
        #pragma unroll
        for (int n = 0; n < 4; n++) {
            size_t off = (size_t)(wc + n * 16 + r16) * D + k0;
            bh[n] = load_bf8(Wh + off);
            bl[n] = load_bf8(Wl + off);
        }
        #pragma unroll
        for (int m = 0; m < 4; m++)
            #pragma unroll
            for (int n = 0; n < 4; n++) {
                acc[m][n] = __builtin_amdgcn_mfma_f32_16x16x32_bf16(ah[m], bh[n], acc[m][n], 0, 0, 0);
                acc[m][n] = __builtin_amdgcn_mfma_f32_16x16x32_bf16(al[m], bh[n], acc[m][n], 0, 0, 0);
                acc[m][n] = __builtin_amdgcn_mfma_f32_16x16x32_bf16(ah[m], bl[n], acc[m][n], 0, 0, 0);
            }
    }

    // C/D layout: col = lane&15, row = (lane>>4)*4 + reg
    #pragma unroll
    for (int n = 0; n < 4; n++) {
        int col = wc + n * 16 + r16;
        float bv = bias ? bias[col] : 0.0f;
        #pragma unroll
        for (int m = 0; m < 4; m++) {
            int rbase = row0 + m * 16 + kg * 4;
            #pragma unroll
            for (int r = 0; r < 4; r++)
                O[(size_t)(rbase + r) * 256 + col] = acc[m][n][r] + bv;
        }
    }
}

// Edge gate + aggregate. 8 nodes/block, 32 lanes/node, float4/lane.
// Graph-affine XCD swizzle; (j,dist) staged in LDS, broadcast via ds_read.
__global__ __launch_bounds__(256) void k_edges(
        const int2* __restrict__ jd,
        const float* __restrict__ AfAs, const float* __restrict__ BfBs,
        const float* __restrict__ wfd, const float* __restrict__ wsd,
        float* __restrict__ agg, int N, int S, int G, int deg) {
    __shared__ int2 jds[512];
    int b = blockIdx.x;
    int node0;
    if ((G & 7) == 0 && (S & 7) == 0) {
        int xcd = b & 7, i = b >> 3;
        int bpg = S >> 3;                       // blocks per graph
        int gi = i / bpg, li = i - gi * bpg;
        node0 = (xcd + 8 * gi) * S + li * 8;    // graph g on XCD g%8
    } else node0 = b * 8;
    int tid = threadIdx.x;
    int grp = tid >> 5, lane = tid & 31;
    bool use_lds = (8 * deg) <= 512;
    if (use_lds) {
        int tot = 8 * deg;
        int lim = (node0 + 8 <= N) ? tot : (N > node0 ? (N - node0) * deg : 0);
        for (int t = tid; t < lim; t += 256) jds[t] = jd[(size_t)node0 * deg + t];
    }
    __syncthreads();
    int node = node0 + grp;
    if (node >= N) return;
    int d0 = lane * 4;
    const f4 af4 = *reinterpret_cast<const f4*>(AfAs + (size_t)node * 256 + d0);
    const f4 as4 = *reinterpret_cast<const f4*>(AfAs + (size_t)node * 256 + 128 + d0);
    const f4 wf4 = *reinterpret_cast<const f4*>(wfd + d0);
    const f4 ws4 = *reinterpret_cast<const f4*>(wsd + d0);
    const int2* jrow = use_lds ? (jds + grp * deg) : (jd + (size_t)node * deg);
    f4 acc = {0.f, 0.f, 0.f, 0.f};
    #pragma unroll 8
    for (int e = 0; e < deg; e++) {
        int2 p = jrow[e];
        float dst = __int_as_float(p.y);
        const f4* bp = reinterpret_cast<const f4*>(BfBs + (size_t)p.x * 256 + d0);
        f4 bf4 = bp[0];
        f4 bs4 = bp[32];          // +128 floats, same base, imm offset
        #pragma unroll
        for (int c = 0; c < 4; c++) {
            float u  = fmaf(dst, wf4[c], af4[c]) + bf4[c];
            float vv = fmaf(dst, ws4[c], as4[c]) + bs4[c];
            float sg = __builtin_amdgcn_rcpf(1.0f + __expf(-u));
            float sp = fmaxf(vv, 0.0f) + __logf(1.0f + __expf(-fabsf(vv)));
            acc[c] = fmaf(sg, sp, acc[c]);
        }
    }
    *reinterpret_cast<f4*>(agg + (size_t)node * D + d0) = acc;
}

// per-feature sum/sumsq of P[N][D] -> atomicAdd (pre-zeroed). float4 per thread.
__global__ __launch_bounds__(256) void k_stats(const float* __restrict__ P,
        float* __restrict__ sums, float* __restrict__ sumsq, int N) {
    __shared__ f4 s1[256], s2[256];
    int tid = threadIdx.x;
    int sl = tid & 31, grp = tid >> 5;
    int d0 = sl * 4;
    f4 a = {0.f, 0.f, 0.f, 0.f}, b = {0.f, 0.f, 0.f, 0.f};
    for (int r = blockIdx.x * 8 + grp; r < N; r += gridDim.x * 8) {
        f4 v = *reinterpret_cast<const f4*>(P + (size_t)r * D + d0);
        a += v;
        b += v * v;
    }
    s1[tid] = a;
    s2[tid] = b;
    __syncthreads();
    if (tid < 64) {
        int which = tid >> 5, l = tid & 31;
        f4 acc = which ? s2[l] : s1[l];
        #pragma unroll
        for (int g = 1; g < 8; g++) acc += which ? s2[g * 32 + l] : s1[g * 32 + l];
        float* dstp = which ? sumsq : sums;
        #pragma unroll
        for (int c = 0; c < 4; c++) atomicAdd(dstp + l * 4 + c, acc[c]);
    }
}

// xnew = gc*(agg-mu1)*rsqrt(var1+eps)+bc+x (in place), accumulate stats of xnew.
__global__ __launch_bounds__(256) void k_bn1res(
        const float* __restrict__ sums1, const float* __restrict__ sumsq1,
        const float* __restrict__ gc, const float* __restrict__ bc,
        const float* __restrict__ x, float* __restrict__ aggxnew,
        float* __restrict__ sums2, float* __restrict__ sumsq2, int N) {
    __shared__ f4 s1[256], s2[256];
    int tid = threadIdx.x;
    int sl = tid & 31, grp = tid >> 5;
    int d0 = sl * 4;
    float invN = 1.0f / (float)N;
    f4 mu = *reinterpret_cast<const f4*>(sums1 + d0);
    f4 sq = *reinterpret_cast<const f4*>(sumsq1 + d0);
    f4 g4 = *reinterpret_cast<const f4*>(gc + d0);
    f4 b4 = *reinterpret_cast<const f4*>(bc + d0);
    f4 inv;
    #pragma unroll
    for (int c = 0; c < 4; c++) {
        float m = mu[c] * invN;
        mu[c] = m;
        inv[c] = rsqrtf(sq[c] * invN - m * m + 1e-5f);
    }
    f4 sa = {0.f, 0.f, 0.f, 0.f}, sb = {0.f, 0.f, 0.f, 0.f};
    for (int r = blockIdx.x * 8 + grp; r < N; r += gridDim.x * 8) {
        size_t idx = (size_t)r * D + d0;
        f4 v = *reinterpret_cast<const f4*>(aggxnew + idx);
        f4 xv = *reinterpret_cast<const f4*>(x + idx);
        f4 xn;
        #pragma unroll
        for (int c = 0; c < 4; c++) xn[c] = fmaf(g4[c] * (v[c] - mu[c]), inv[c], b4[c]) + xv[c];
        *reinterpret_cast<f4*>(aggxnew + idx) = xn;
        sa += xn;
        sb += xn * xn;
    }
    s1[tid] = sa;
    s2[tid] = sb;
    __syncthreads();
    if (tid < 64) {
        int which = tid >> 5, l = tid & 31;
        f4 acc = which ? s2[l] : s1[l];
        #pragma unroll
        for (int g = 1; g < 8; g++) acc += which ? s2[g * 32 + l] : s1[g * 32 + l];
        float* dstp = which ? sumsq2 : sums2;
        #pragma unroll
        for (int c = 0; c < 4; c++) atomicAdd(dstp + l * 4 + c, acc[c]);
    }
}

// x = relu(gn*(xnew-mu2)*rsqrt(var2+eps)+bnb); emit bf16 hi/lo. float4 per thread.
__global__ __launch_bounds__(256) void k_bn2relu(
        const float* __restrict__ sums2, const float* __restrict__ sumsq2,
        const float* __restrict__ gn, const float* __restrict__ bnb,
        const float* __restrict__ xnew, float* __restrict__ xout,
        unsigned short* __restrict__ xh, unsigned short* __restrict__ xl, int N) {
    int idx = blockIdx.x * blockDim.x + threadIdx.x;      // N*32 threads
    if (idx >= N * 32) return;
    int n = idx >> 5;
    int d0 = (idx & 31) * 4;
    float invN = 1.0f / (float)N;
    f4 mu = *reinterpret_cast<const f4*>(sums2 + d0);
    f4 sq = *reinterpret_cast<const f4*>(sumsq2 + d0);
    f4 g4 = *reinterpret_cast<const f4*>(gn + d0);
    f4 b4 = *reinterpret_cast<const f4*>(bnb + d0);
    f4 v = *reinterpret_cast<const f4*>(xnew + (size_t)n * D + d0);
    f4 o;
    u16x4 h, l;
    #pragma unroll
    for (int c = 0; c < 4; c++) {
        float m = mu[c] * invN;
        float inv = rsqrtf(sq[c] * invN - m * m + 1e-5f);
        float t = fmaf(g4[c] * (v[c] - m), inv, b4[c]);
        t = fmaxf(t, 0.0f);
        o[c] = t;
        h[c] = f2bf(t);
        l[c] = f2bf(t - bf2f(h[c]));
    }
    *reinterpret_cast<f4*>(xout + (size_t)n * D + d0) = o;
    *reinterpret_cast<u16x4*>(xh + (size_t)n * D + d0) = h;
    *reinterpret_cast<u16x4*>(xl + (size_t)n * D + d0) = l;
}

// Per-graph feature sums: 8 blocks per graph, atomicAdd into gsum[G][D] (pre-zeroed)
__global__ __launch_bounds__(256) void k_pool(const float* __restrict__ x,
        float* __restrict__ gsum, int S) {
    __shared__ f4 s[256];
    int b = blockIdx.x;
    int g = b >> 3, sub = b & 7;
    int tid = threadIdx.x;
    int grp = tid >> 5, lane = tid & 31;
    int d0 = lane * 4;
    f4 a = {0.f, 0.f, 0.f, 0.f};
    for (int r = sub * 8 + grp; r < S; r += 64)
        a += *reinterpret_cast<const f4*>(x + ((size_t)g * S + r) * D + d0);
    s[tid] = a;
    __syncthreads();
    if (tid < 32) {
        f4 acc = s[tid];
        #pragma unroll
        for (int q = 1; q < 8; q++) acc += s[q * 32 + tid];
        #pragma unroll
        for (int c = 0; c < 4; c++) atomicAdd(&gsum[g * D + tid * 4 + c], acc[c]);
    }
}

// out[g] = relu(gmean@W1+b1) @ W2 + b2
__global__ __launch_bounds__(128) void k_mlp(const float* __restrict__ gsum,
        const float* __restrict__ W1, const float* __restrict__ b1,
        const float* __restrict__ W2, const float* __restrict__ b2,
        float* __restrict__ out, int S) {
    __shared__ float gm[D];
    __shared__ float red[128];
    int g = blockIdx.x, d = threadIdx.x;
    gm[d] = gsum[g * D + d] / (float)S;
    __syncthreads();
    float h = b1[d];
    #pragma unroll 8
    for (int k = 0; k < D; k++) h = fmaf(gm[k], W1[k * D + d], h);
    h = fmaxf(h, 0.0f);
    red[d] = h * W2[d];
    __syncthreads();
    for (int st = 64; st > 0; st >>= 1) {
        if (d < st) red[d] += red[d + st];
        __syncthreads();
    }
    if (d == 0) out[g] = red[0] + b2[0];
}

extern "C" void kernel_launch(void* const* d_in, const int* in_sizes, int n_in,
                              void* d_out, int out_size, void* d_ws, size_t ws_size,
                              hipStream_t stream) {
    const int*   z    = (const int*)d_in[0];
    const float* pos  = (const float*)d_in[1];
    const int*   eidx = (const int*)d_in[3];
    const float* emb  = (const float*)d_in[4];
    const float* Wf   = (const float*)d_in[5];
    const float* bf   = (const float*)d_in[6];
    const float* Ws   = (const float*)d_in[7];
    const float* bs   = (const float*)d_in[8];
    const float* gc   = (const float*)d_in[9];
    const float* bc   = (const float*)d_in[10];
    const float* gn   = (const float*)d_in[11];
    const float* bnb  = (const float*)d_in[12];
    const float* W1   = (const float*)d_in[13];
    const float* b1   = (const float*)d_in[14];
    const float* W2   = (const float*)d_in[15];
    const float* b2   = (const float*)d_in[16];

    int N = in_sizes[0];
    int E = in_sizes[3] / 2;
    int L = in_sizes[6] / D;
    int deg = E / N;
    int G = out_size;
    int S = N / G;

    const int* row = eidx;
    const int* col = eidx + E;

    float* ws = (float*)d_ws;
    size_t nd = (size_t)N * D;
    float* x    = ws;                  // [N][128]
    float* AfAs = x + nd;              // [N][256]
    float* BfBs = AfAs + 2 * nd;       // [N][256]
    float* agg  = BfBs + 2 * nd;       // [N][128], reused as xnew in place
    int2*  jd   = (int2*)(agg + nd);   // [E] packed (j, dist)
    unsigned short* xh  = (unsigned short*)(jd + E);
    unsigned short* xl  = xh + nd;
    unsigned short* Wth = xl + nd;                          // L*4*128*128 bf16
    unsigned short* Wtl = Wth + (size_t)L * 4 * D * D;
    float* stats = (float*)(Wtl + (size_t)L * 4 * D * D);   // L*512 floats
    float* gsum  = stats + (size_t)L * 512;                 // G*128 floats

    hipMemsetAsync(stats, 0, ((size_t)L * 512 + (size_t)G * D) * sizeof(float), stream);

    k_cvtW<<<(L * 4 * D * D + 255) / 256, 256, 0, stream>>>(Wf, Ws, Wth, Wtl, L);
    k_embed<<<(N * 32 + 255) / 256, 256, 0, stream>>>(z, emb, x, xh, xl, N);
    k_dist<<<(E + 255) / 256, 256, 0, stream>>>(row, col, pos, jd, E);

    for (int l = 0; l < L; ++l) {
        const float* Wfl = Wf + (size_t)l * 257 * D;
        const float* Wsl = Ws + (size_t)l * 257 * D;
        float* st = stats + (size_t)l * 512;
        k_gemm_mfma<<<dim3(N / 128, 4), 256, 0, stream>>>(
            xh, xl, Wth + (size_t)l * 4 * D * D, Wtl + (size_t)l * 4 * D * D,
            bf + l * D, bs + l * D, AfAs, BfBs, S, G);
        k_edges<<<(N + 7) / 8, 256, 0, stream>>>(jd, AfAs, BfBs,
                                                 Wfl + 256 * D, Wsl + 256 * D, agg, N, S, G, deg);
        k_stats<<<256, 256, 0, stream>>>(agg, st, st + 128, N);
        k_bn1res<<<256, 256, 0, stream>>>(st, st + 128, gc + l * D, bc + l * D,
                                          x, agg, st + 256, st + 384, N);
        k_bn2relu<<<(N * 32 + 255) / 256, 256, 0, stream>>>(st + 256, st + 384,
                                                            gn + l * D, bnb + l * D, agg, x, xh, xl, N);
    }
    k_pool<<<G * 8, 256, 0, stream>>>(x, gsum, S);
    k_mlp<<<G, 128, 0, stream>>>(gsum, W1, b1, W2, b2, (float*)d_out, S);
}

// Round 5
// 713.347 us; speedup vs baseline: 1.4912x; 1.2239x over previous
//
#include <hip/hip_runtime.h>
#include <math.h>

#define D 128
#define LOG2E 1.44269504f

typedef short bf16x8 __attribute__((ext_vector_type(8)));
typedef float f32x4 __attribute__((ext_vector_type(4)));
typedef float f4 __attribute__((ext_vector_type(4)));
typedef unsigned short u16x4 __attribute__((ext_vector_type(4)));

__device__ __forceinline__ unsigned short f2bf(float f) {
    unsigned int u = __float_as_uint(f);
    u += 0x7fff + ((u >> 16) & 1);   // round-to-nearest-even
    return (unsigned short)(u >> 16);
}
__device__ __forceinline__ float bf2f(unsigned short h) {
    return __uint_as_float(((unsigned int)h) << 16);
}
__device__ __forceinline__ bf16x8 load_bf8(const unsigned short* p) {
    return __builtin_bit_cast(bf16x8, *reinterpret_cast<const uint4*>(p));
}
// raw HW transcendentals (v_exp_f32 = 2^x, v_log_f32 = log2)
__device__ __forceinline__ float exp2_hw(float x) {
    float r; asm("v_exp_f32 %0, %1" : "=v"(r) : "v"(x)); return r;
}
__device__ __forceinline__ float log2_hw(float x) {
    float r; asm("v_log_f32 %0, %1" : "=v"(r) : "v"(x)); return r;
}

// x[n][d] = emb[z[n]][d]; also emit bf16 hi/lo split. float4 per thread.
__global__ __launch_bounds__(256) void k_embed(const int* __restrict__ z,
        const float* __restrict__ emb, float* __restrict__ x,
        unsigned short* __restrict__ xh, unsigned short* __restrict__ xl, int N) {
    int idx = blockIdx.x * blockDim.x + threadIdx.x;       // N*32 threads
    if (idx >= N * 32) return;
    int n = idx >> 5;
    int d0 = (idx & 31) * 4;
    f4 v = *reinterpret_cast<const f4*>(emb + (size_t)z[n] * D + d0);
    *reinterpret_cast<f4*>(x + (size_t)n * D + d0) = v;
    u16x4 h, l;
    #pragma unroll
    for (int c = 0; c < 4; c++) {
        h[c] = f2bf(v[c]);
        l[c] = f2bf(v[c] - bf2f(h[c]));
    }
    *reinterpret_cast<u16x4*>(xh + (size_t)n * D + d0) = h;
    *reinterpret_cast<u16x4*>(xl + (size_t)n * D + d0) = l;
}

// jd[e] = (row[e], bits(||pos[row]-pos[col]||)) packed
__global__ void k_dist(const int* __restrict__ row, const int* __restrict__ col,
                       const float* __restrict__ pos, int2* __restrict__ jd, int E) {
    int e = blockIdx.x * blockDim.x + threadIdx.x;
    if (e >= E) return;
    int r = row[e], c = col[e];
    float dx = pos[3 * r + 0] - pos[3 * c + 0];
    float dy = pos[3 * r + 1] - pos[3 * c + 1];
    float dz = pos[3 * r + 2] - pos[3 * c + 2];
    float dist = sqrtf(dx * dx + dy * dy + dz * dz);
    jd[e] = make_int2(r, __float_as_int(dist));
}

// Pre-transpose + bf16 hi/lo split all layer weights, PRE-SCALED for base-2 gate:
// f-path (mats 0,1) x (-log2e), s-path (mats 2,3) x (+log2e).
__global__ void k_cvtW(const float* __restrict__ Wf, const float* __restrict__ Ws,
                       unsigned short* __restrict__ Wth, unsigned short* __restrict__ Wtl,
                       int L) {
    int idx = blockIdx.x * blockDim.x + threadIdx.x;
    if (idx >= L * 4 * D * D) return;
    int k = idx & 127;
    int n = (idx >> 7) & 127;
    int mat = (idx >> 14) & 3;
    int l = idx >> 16;
    const float* src = (mat < 2) ? Wf : Ws;
    float scale = (mat < 2) ? -LOG2E : LOG2E;
    float v = scale * src[(size_t)l * 257 * D + (size_t)((mat & 1) * D + k) * D + n];
    unsigned short h = f2bf(v);
    Wth[idx] = h;
    Wtl[idx] = f2bf(v - bf2f(h));
}

// Split-bf16 MFMA GEMM, graph-affine XCD swizzle on row tiles.
// Outputs interleaved: AfAs[N][256] = [Af|As], BfBs[N][256] = [Bf|Bs]  (pre-scaled)
__global__ __launch_bounds__(256) void k_gemm_mfma(
        const unsigned short* __restrict__ Xh, const unsigned short* __restrict__ Xl,
        const unsigned short* __restrict__ Wth, const unsigned short* __restrict__ Wtl,
        const float* __restrict__ bfl, const float* __restrict__ bsl,
        float* __restrict__ AfAs, float* __restrict__ BfBs, int S, int G) {
    int mat = blockIdx.y;                      // 0=Af 1=Bf 2=As 3=Bs
    float* O = ((mat & 1) ? BfBs : AfAs) + ((mat >> 1) ? 128 : 0);
    const float* bias = (mat == 0) ? bfl : (mat == 2) ? bsl : nullptr;
    float bsc = (mat == 0) ? -LOG2E : LOG2E;
    const unsigned short* Wh = Wth + (size_t)mat * D * D;
    const unsigned short* Wl = Wtl + (size_t)mat * D * D;

    int wave = threadIdx.x >> 6;
    int lane = threadIdx.x & 63;
    int r16 = lane & 15;
    int kg = lane >> 4;

    int xb = blockIdx.x;
    int tile0;
    if ((G & 7) == 0 && (S & 127) == 0) {
        int xcd = xb & 7, i = xb >> 3;
        int tpg = S >> 7;                       // 128-row tiles per graph
        int gi = i / tpg, t = i - gi * tpg;
        tile0 = (xcd + 8 * gi) * S + t * 128;   // graph g on XCD g%8
    } else tile0 = xb * 128;
    int row0 = tile0 + (wave >> 1) * 64;
    int wc = (wave & 1) * 64;

    f32x4 acc[4][4];
    #pragma unroll
    for (int m = 0; m < 4; m++)
        #pragma unroll
        for (int n = 0; n < 4; n++) acc[m][n] = (f32x4){0.f, 0.f, 0.f, 0.f};

    #pragma unroll
    for (int ks = 0; ks < 4; ++ks) {
        int k0 = ks * 32 + kg * 8;
        bf16x8 ah[4], al[4], bh[4], bl[4];
        #pragma unroll
        for (int m = 0; m < 4; m++) {
            size_t off = (size_t)(row0 + m * 16 + r16) * D + k0;
            ah[m] = load_bf8(Xh + off);
            al[m] = load_bf8(Xl + off);
        }
        #pragma unroll
        for (int n = 0; n < 4; n++) {
            size_t off = (size_t)(wc + n * 16 + r16) * D + k0;
            bh[n] = load_bf8(Wh + off);
            bl[n] = load_bf8(Wl + off);
        }
        #pragma unroll
        for (int m = 0; m < 4; m++)
            #pragma unroll
            for (int n = 0; n < 4; n++) {
                acc[m][n] = __builtin_amdgcn_mfma_f32_16x16x32_bf16(ah[m], bh[n], acc[m][n], 0, 0, 0);
                acc[m][n] = __builtin_amdgcn_mfma_f32_16x16x32_bf16(al[m], bh[n], acc[m][n], 0, 0, 0);
                acc[m][n] = __builtin_amdgcn_mfma_f32_16x16x32_bf16(ah[m], bl[n], acc[m][n], 0, 0, 0);
            }
    }

    // C/D layout: col = lane&15, row = (lane>>4)*4 + reg
    #pragma unroll
    for (int n = 0; n < 4; n++) {
        int col = wc + n * 16 + r16;
        float bv = bias ? bias[col] * bsc : 0.0f;
        #pragma unroll
        for (int m = 0; m < 4; m++) {
            int rbase = row0 + m * 16 + kg * 4;
            #pragma unroll
            for (int r = 0; r < 4; r++)
                O[(size_t)(rbase + r) * 256 + col] = acc[m][n][r] + bv;
        }
    }
}

// Edge gate + aggregate, base-2 folded math (output = true agg / ln2; BN-invariant).
// 8 nodes/block, 32 lanes/node, float4/lane; graph-affine XCD swizzle.
__global__ __launch_bounds__(256) void k_edges(
        const int2* __restrict__ jd,
        const float* __restrict__ AfAs, const float* __restrict__ BfBs,
        const float* __restrict__ wfd, const float* __restrict__ wsd,
        float* __restrict__ agg, int N, int S, int G, int deg) {
    __shared__ int2 jds[512];
    int b = blockIdx.x;
    int node0;
    if ((G & 7) == 0 && (S & 7) == 0) {
        int xcd = b & 7, i = b >> 3;
        int bpg = S >> 3;                       // blocks per graph
        int gi = i / bpg, li = i - gi * bpg;
        node0 = (xcd + 8 * gi) * S + li * 8;    // graph g on XCD g%8
    } else node0 = b * 8;
    int tid = threadIdx.x;
    int grp = tid >> 5, lane = tid & 31;
    bool use_lds = (8 * deg) <= 512;
    if (use_lds) {
        int tot = 8 * deg;
        int lim = (node0 + 8 <= N) ? tot : (N > node0 ? (N - node0) * deg : 0);
        for (int t = tid; t < lim; t += 256) jds[t] = jd[(size_t)node0 * deg + t];
    }
    __syncthreads();
    int node = node0 + grp;
    if (node >= N) return;
    int d0 = lane * 4;
    const f4 af4 = *reinterpret_cast<const f4*>(AfAs + (size_t)node * 256 + d0);
    const f4 as4 = *reinterpret_cast<const f4*>(AfAs + (size_t)node * 256 + 128 + d0);
    const f4 wf4 = *reinterpret_cast<const f4*>(wfd + d0) * (-LOG2E);
    const f4 ws4 = *reinterpret_cast<const f4*>(wsd + d0) * (LOG2E);
    const int2* jrow = use_lds ? (jds + grp * deg) : (jd + (size_t)node * deg);
    f4 acc = {0.f, 0.f, 0.f, 0.f};
    #pragma unroll 8
    for (int e = 0; e < deg; e++) {
        int2 p = jrow[e];
        float dst = __int_as_float(p.y);
        int off = (p.x << 8) + d0;              // 32-bit offset, BfBs < 2^31 elems
        f4 bf4 = *reinterpret_cast<const f4*>(BfBs + off);
        f4 bs4 = *reinterpret_cast<const f4*>(BfBs + off + 128);
        #pragma unroll
        for (int c = 0; c < 4; c++) {
            float u2 = fmaf(dst, wf4[c], af4[c]) + bf4[c];   // = -log2e * u
            float v2 = fmaf(dst, ws4[c], as4[c]) + bs4[c];   // = +log2e * v
            float s = exp2_hw(u2);                            // e^{-u}
            float t = exp2_hw(v2);                            // e^{v}
            float sg = __builtin_amdgcn_rcpf(1.0f + s);       // sigmoid(u)
            float sp = log2_hw(1.0f + t);                     // softplus(v)/ln2
            acc[c] = fmaf(sg, sp, acc[c]);
        }
    }
    *reinterpret_cast<f4*>(agg + (size_t)node * D + d0) = acc;
}

// per-feature sum/sumsq of P[N][D] -> atomicAdd (pre-zeroed). float4 per thread.
__global__ __launch_bounds__(256) void k_stats(const float* __restrict__ P,
        float* __restrict__ sums, float* __restrict__ sumsq, int N) {
    __shared__ f4 s1[256], s2[256];
    int tid = threadIdx.x;
    int sl = tid & 31, grp = tid >> 5;
    int d0 = sl * 4;
    f4 a = {0.f, 0.f, 0.f, 0.f}, b = {0.f, 0.f, 0.f, 0.f};
    for (int r = blockIdx.x * 8 + grp; r < N; r += gridDim.x * 8) {
        f4 v = *reinterpret_cast<const f4*>(P + (size_t)r * D + d0);
        a += v;
        b += v * v;
    }
    s1[tid] = a;
    s2[tid] = b;
    __syncthreads();
    if (tid < 64) {
        int which = tid >> 5, l = tid & 31;
        f4 acc = which ? s2[l] : s1[l];
        #pragma unroll
        for (int g = 1; g < 8; g++) acc += which ? s2[g * 32 + l] : s1[g * 32 + l];
        float* dstp = which ? sumsq : sums;
        #pragma unroll
        for (int c = 0; c < 4; c++) atomicAdd(dstp + l * 4 + c, acc[c]);
    }
}

// xnew = gc*(agg-mu1)*rsqrt(var1+eps)+bc+x (in place), accumulate stats of xnew.
__global__ __launch_bounds__(256) void k_bn1res(
        const float* __restrict__ sums1, const float* __restrict__ sumsq1,
        const float* __restrict__ gc, const float* __restrict__ bc,
        const float* __restrict__ x, float* __restrict__ aggxnew,
        float* __restrict__ sums2, float* __restrict__ sumsq2, int N) {
    __shared__ f4 s1[256], s2[256];
    int tid = threadIdx.x;
    int sl = tid & 31, grp = tid >> 5;
    int d0 = sl * 4;
    float invN = 1.0f / (float)N;
    f4 mu = *reinterpret_cast<const f4*>(sums1 + d0);
    f4 sq = *reinterpret_cast<const f4*>(sumsq1 + d0);
    f4 g4 = *reinterpret_cast<const f4*>(gc + d0);
    f4 b4 = *reinterpret_cast<const f4*>(bc + d0);
    f4 inv;
    #pragma unroll
    for (int c = 0; c < 4; c++) {
        float m = mu[c] * invN;
        mu[c] = m;
        inv[c] = rsqrtf(sq[c] * invN - m * m + 1e-5f);
    }
    f4 sa = {0.f, 0.f, 0.f, 0.f}, sb = {0.f, 0.f, 0.f, 0.f};
    for (int r = blockIdx.x * 8 + grp; r < N; r += gridDim.x * 8) {
        size_t idx = (size_t)r * D + d0;
        f4 v = *reinterpret_cast<const f4*>(aggxnew + idx);
        f4 xv = *reinterpret_cast<const f4*>(x + idx);
        f4 xn;
        #pragma unroll
        for (int c = 0; c < 4; c++) xn[c] = fmaf(g4[c] * (v[c] - mu[c]), inv[c], b4[c]) + xv[c];
        *reinterpret_cast<f4*>(aggxnew + idx) = xn;
        sa += xn;
        sb += xn * xn;
    }
    s1[tid] = sa;
    s2[tid] = sb;
    __syncthreads();
    if (tid < 64) {
        int which = tid >> 5, l = tid & 31;
        f4 acc = which ? s2[l] : s1[l];
        #pragma unroll
        for (int g = 1; g < 8; g++) acc += which ? s2[g * 32 + l] : s1[g * 32 + l];
        float* dstp = which ? sumsq2 : sums2;
        #pragma unroll
        for (int c = 0; c < 4; c++) atomicAdd(dstp + l * 4 + c, acc[c]);
    }
}

// x = relu(gn*(xnew-mu2)*rsqrt(var2+eps)+bnb); emit bf16 hi/lo. float4 per thread.
__global__ __launch_bounds__(256) void k_bn2relu(
        const float* __restrict__ sums2, const float* __restrict__ sumsq2,
        const float* __restrict__ gn, const float* __restrict__ bnb,
        const float* __restrict__ xnew, float* __restrict__ xout,
        unsigned short* __restrict__ xh, unsigned short* __restrict__ xl, int N) {
    int idx = blockIdx.x * blockDim.x + threadIdx.x;      // N*32 threads
    if (idx >= N * 32) return;
    int n = idx >> 5;
    int d0 = (idx & 31) * 4;
    float invN = 1.0f / (float)N;
    f4 mu = *reinterpret_cast<const f4*>(sums2 + d0);
    f4 sq = *reinterpret_cast<const f4*>(sumsq2 + d0);
    f4 g4 = *reinterpret_cast<const f4*>(gn + d0);
    f4 b4 = *reinterpret_cast<const f4*>(bnb + d0);
    f4 v = *reinterpret_cast<const f4*>(xnew + (size_t)n * D + d0);
    f4 o;
    u16x4 h, l;
    #pragma unroll
    for (int c = 0; c < 4; c++) {
        float m = mu[c] * invN;
        float inv = rsqrtf(sq[c] * invN - m * m + 1e-5f);
        float t = fmaf(g4[c] * (v[c] - m), inv, b4[c]);
        t = fmaxf(t, 0.0f);
        o[c] = t;
        h[c] = f2bf(t);
        l[c] = f2bf(t - bf2f(h[c]));
    }
    *reinterpret_cast<f4*>(xout + (size_t)n * D + d0) = o;
    *reinterpret_cast<u16x4*>(xh + (size_t)n * D + d0) = h;
    *reinterpret_cast<u16x4*>(xl + (size_t)n * D + d0) = l;
}

// Per-graph feature sums: 8 blocks per graph, atomicAdd into gsum[G][D] (pre-zeroed)
__global__ __launch_bounds__(256) void k_pool(const float* __restrict__ x,
        float* __restrict__ gsum, int S) {
    __shared__ f4 s[256];
    int b = blockIdx.x;
    int g = b >> 3, sub = b & 7;
    int tid = threadIdx.x;
    int grp = tid >> 5, lane = tid & 31;
    int d0 = lane * 4;
    f4 a = {0.f, 0.f, 0.f, 0.f};
    for (int r = sub * 8 + grp; r < S; r += 64)
        a += *reinterpret_cast<const f4*>(x + ((size_t)g * S + r) * D + d0);
    s[tid] = a;
    __syncthreads();
    if (tid < 32) {
        f4 acc = s[tid];
        #pragma unroll
        for (int q = 1; q < 8; q++) acc += s[q * 32 + tid];
        #pragma unroll
        for (int c = 0; c < 4; c++) atomicAdd(&gsum[g * D + tid * 4 + c], acc[c]);
    }
}

// out[g] = relu(gmean@W1+b1) @ W2 + b2
__global__ __launch_bounds__(128) void k_mlp(const float* __restrict__ gsum,
        const float* __restrict__ W1, const float* __restrict__ b1,
        const float* __restrict__ W2, const float* __restrict__ b2,
        float* __restrict__ out, int S) {
    __shared__ float gm[D];
    __shared__ float red[128];
    int g = blockIdx.x, d = threadIdx.x;
    gm[d] = gsum[g * D + d] / (float)S;
    __syncthreads();
    float h = b1[d];
    #pragma unroll 8
    for (int k = 0; k < D; k++) h = fmaf(gm[k], W1[k * D + d], h);
    h = fmaxf(h, 0.0f);
    red[d] = h * W2[d];
    __syncthreads();
    for (int st = 64; st > 0; st >>= 1) {
        if (d < st) red[d] += red[d + st];
        __syncthreads();
    }
    if (d == 0) out[g] = red[0] + b2[0];
}

extern "C" void kernel_launch(void* const* d_in, const int* in_sizes, int n_in,
                              void* d_out, int out_size, void* d_ws, size_t ws_size,
                              hipStream_t stream) {
    const int*   z    = (const int*)d_in[0];
    const float* pos  = (const float*)d_in[1];
    const int*   eidx = (const int*)d_in[3];
    const float* emb  = (const float*)d_in[4];
    const float* Wf   = (const float*)d_in[5];
    const float* bf   = (const float*)d_in[6];
    const float* Ws   = (const float*)d_in[7];
    const float* bs   = (const float*)d_in[8];
    const float* gc   = (const float*)d_in[9];
    const float* bc   = (const float*)d_in[10];
    const float* gn   = (const float*)d_in[11];
    const float* bnb  = (const float*)d_in[12];
    const float* W1   = (const float*)d_in[13];
    const float* b1   = (const float*)d_in[14];
    const float* W2   = (const float*)d_in[15];
    const float* b2   = (const float*)d_in[16];

    int N = in_sizes[0];
    int E = in_sizes[3] / 2;
    int L = in_sizes[6] / D;
    int deg = E / N;
    int G = out_size;
    int S = N / G;

    const int* row = eidx;
    const int* col = eidx + E;

    float* ws = (float*)d_ws;
    size_t nd = (size_t)N * D;
    float* x    = ws;                  // [N][128]
    float* AfAs = x + nd;              // [N][256]
    float* BfBs = AfAs + 2 * nd;       // [N][256]
    float* agg  = BfBs + 2 * nd;       // [N][128], reused as xnew in place
    int2*  jd   = (int2*)(agg + nd);   // [E] packed (j, dist)
    unsigned short* xh  = (unsigned short*)(jd + E);
    unsigned short* xl  = xh + nd;
    unsigned short* Wth = xl + nd;                          // L*4*128*128 bf16
    unsigned short* Wtl = Wth + (size_t)L * 4 * D * D;
    float* stats = (float*)(Wtl + (size_t)L * 4 * D * D);   // L*512 floats
    float* gsum  = stats + (size_t)L * 512;                 // G*128 floats

    hipMemsetAsync(stats, 0, ((size_t)L * 512 + (size_t)G * D) * sizeof(float), stream);

    k_cvtW<<<(L * 4 * D * D + 255) / 256, 256, 0, stream>>>(Wf, Ws, Wth, Wtl, L);
    k_embed<<<(N * 32 + 255) / 256, 256, 0, stream>>>(z, emb, x, xh, xl, N);
    k_dist<<<(E + 255) / 256, 256, 0, stream>>>(row, col, pos, jd, E);

    for (int l = 0; l < L; ++l) {
        const float* Wfl = Wf + (size_t)l * 257 * D;
        const float* Wsl = Ws + (size_t)l * 257 * D;
        float* st = stats + (size_t)l * 512;
        k_gemm_mfma<<<dim3(N / 128, 4), 256, 0, stream>>>(
            xh, xl, Wth + (size_t)l * 4 * D * D, Wtl + (size_t)l * 4 * D * D,
            bf + l * D, bs + l * D, AfAs, BfBs, S, G);
        k_edges<<<(N + 7) / 8, 256, 0, stream>>>(jd, AfAs, BfBs,
                                                 Wfl + 256 * D, Wsl + 256 * D, agg, N, S, G, deg);
        k_stats<<<256, 256, 0, stream>>>(agg, st, st + 128, N);
        k_bn1res<<<256, 256, 0, stream>>>(st, st + 128, gc + l * D, bc + l * D,
                                          x, agg, st + 256, st + 384, N);
        k_bn2relu<<<(N * 32 + 255) / 256, 256, 0, stream>>>(st + 256, st + 384,
                                                            gn + l * D, bnb + l * D, agg, x, xh, xl, N);
    }
    k_pool<<<G * 8, 256, 0, stream>>>(x, gsum, S);
    k_mlp<<<G, 128, 0, stream>>>(gsum, W1, b1, W2, b2, (float*)d_out, S);
}

// Round 6
// 651.109 us; speedup vs baseline: 1.6338x; 1.0956x over previous
//
#include <hip/hip_runtime.h>
#include <math.h>

#define D 128
#define LOG2E 1.44269504f

typedef short bf16x8 __attribute__((ext_vector_type(8)));
typedef float f32x4 __attribute__((ext_vector_type(4)));
typedef float f4 __attribute__((ext_vector_type(4)));
typedef float f2 __attribute__((ext_vector_type(2)));
typedef unsigned short u16x4 __attribute__((ext_vector_type(4)));

__device__ __forceinline__ unsigned short f2bf(float f) {
    unsigned int u = __float_as_uint(f);
    u += 0x7fff + ((u >> 16) & 1);   // round-to-nearest-even
    return (unsigned short)(u >> 16);
}
__device__ __forceinline__ float bf2f(unsigned short h) {
    return __uint_as_float(((unsigned int)h) << 16);
}
__device__ __forceinline__ bf16x8 load_bf8(const unsigned short* p) {
    return __builtin_bit_cast(bf16x8, *reinterpret_cast<const uint4*>(p));
}
// raw HW transcendentals (v_exp_f32 = 2^x, v_log_f32 = log2)
__device__ __forceinline__ float exp2_hw(float x) {
    float r; asm("v_exp_f32 %0, %1" : "=v"(r) : "v"(x)); return r;
}
__device__ __forceinline__ float log2_hw(float x) {
    float r; asm("v_log_f32 %0, %1" : "=v"(r) : "v"(x)); return r;
}
// packed fp32 (VOP3P)
__device__ __forceinline__ f2 pk_fma(f2 a, f2 b, f2 c) {
    f2 r; asm("v_pk_fma_f32 %0, %1, %2, %3" : "=v"(r) : "v"(a), "v"(b), "v"(c)); return r;
}
__device__ __forceinline__ f2 pk_add(f2 a, f2 b) {
    f2 r; asm("v_pk_add_f32 %0, %1, %2" : "=v"(r) : "v"(a), "v"(b)); return r;
}

// x[n][d] = emb[z[n]][d]; also emit bf16 hi/lo split. float4 per thread.
__global__ __launch_bounds__(256) void k_embed(const int* __restrict__ z,
        const float* __restrict__ emb, float* __restrict__ x,
        unsigned short* __restrict__ xh, unsigned short* __restrict__ xl, int N) {
    int idx = blockIdx.x * blockDim.x + threadIdx.x;       // N*32 threads
    if (idx >= N * 32) return;
    int n = idx >> 5;
    int d0 = (idx & 31) * 4;
    f4 v = *reinterpret_cast<const f4*>(emb + (size_t)z[n] * D + d0);
    *reinterpret_cast<f4*>(x + (size_t)n * D + d0) = v;
    u16x4 h, l;
    #pragma unroll
    for (int c = 0; c < 4; c++) {
        h[c] = f2bf(v[c]);
        l[c] = f2bf(v[c] - bf2f(h[c]));
    }
    *reinterpret_cast<u16x4*>(xh + (size_t)n * D + d0) = h;
    *reinterpret_cast<u16x4*>(xl + (size_t)n * D + d0) = l;
}

// jd[e] = (row[e], bits(||pos[row]-pos[col]||)) packed
__global__ void k_dist(const int* __restrict__ row, const int* __restrict__ col,
                       const float* __restrict__ pos, int2* __restrict__ jd, int E) {
    int e = blockIdx.x * blockDim.x + threadIdx.x;
    if (e >= E) return;
    int r = row[e], c = col[e];
    float dx = pos[3 * r + 0] - pos[3 * c + 0];
    float dy = pos[3 * r + 1] - pos[3 * c + 1];
    float dz = pos[3 * r + 2] - pos[3 * c + 2];
    float dist = sqrtf(dx * dx + dy * dy + dz * dz);
    jd[e] = make_int2(r, __float_as_int(dist));
}

// Pre-transpose + bf16 hi/lo split all layer weights, PRE-SCALED for base-2 gate:
// f-path (mats 0,1) x (-log2e), s-path (mats 2,3) x (+log2e).
__global__ void k_cvtW(const float* __restrict__ Wf, const float* __restrict__ Ws,
                       unsigned short* __restrict__ Wth, unsigned short* __restrict__ Wtl,
                       int L) {
    int idx = blockIdx.x * blockDim.x + threadIdx.x;
    if (idx >= L * 4 * D * D) return;
    int k = idx & 127;
    int n = (idx >> 7) & 127;
    int mat = (idx >> 14) & 3;
    int l = idx >> 16;
    const float* src = (mat < 2) ? Wf : Ws;
    float scale = (mat < 2) ? -LOG2E : LOG2E;
    float v = scale * src[(size_t)l * 257 * D + (size_t)((mat & 1) * D + k) * D + n];
    unsigned short h = f2bf(v);
    Wth[idx] = h;
    Wtl[idx] = f2bf(v - bf2f(h));
}

// Split-bf16 MFMA GEMM, graph-affine XCD swizzle on row tiles.
// Outputs interleaved: AfAs[N][256] = [Af|As], BfBs[N][256] = [Bf|Bs]  (pre-scaled)
__global__ __launch_bounds__(256) void k_gemm_mfma(
        const unsigned short* __restrict__ Xh, const unsigned short* __restrict__ Xl,
        const unsigned short* __restrict__ Wth, const unsigned short* __restrict__ Wtl,
        const float* __restrict__ bfl, const float* __restrict__ bsl,
        float* __restrict__ AfAs, float* __restrict__ BfBs, int S, int G) {
    int mat = blockIdx.y;                      // 0=Af 1=Bf 2=As 3=Bs
    float* O = ((mat & 1) ? BfBs : AfAs) + ((mat >> 1) ? 128 : 0);
    const float* bias = (mat == 0) ? bfl : (mat == 2) ? bsl : nullptr;
    float bsc = (mat == 0) ? -LOG2E : LOG2E;
    const unsigned short* Wh = Wth + (size_t)mat * D * D;
    const unsigned short* Wl = Wtl + (size_t)mat * D * D;

    int wave = threadIdx.x >> 6;
    int lane = threadIdx.x & 63;
    int r16 = lane & 15;
    int kg = lane >> 4;

    int xb = blockIdx.x;
    int tile0;
    if ((G & 7) == 0 && (S & 127) == 0) {
        int xcd = xb & 7, i = xb >> 3;
        int tpg = S >> 7;                       // 128-row tiles per graph
        int gi = i / tpg, t = i - gi * tpg;
        tile0 = (xcd + 8 * gi) * S + t * 128;   // graph g on XCD g%8
    } else tile0 = xb * 128;
    int row0 = tile0 + (wave >> 1) * 64;
    int wc = (wave & 1) * 64;

    f32x4 acc[4][4];
    #pragma unroll
    for (int m = 0; m < 4; m++)
        #pragma unroll
        for (int n = 0; n < 4; n++) acc[m][n] = (f32x4){0.f, 0.f, 0.f, 0.f};

    #pragma unroll
    for (int ks = 0; ks < 4; ++ks) {
        int k0 = ks * 32 + kg * 8;
        bf16x8 ah[4], al[4], bh[4], bl[4];
        #pragma unroll
        for (int m = 0; m < 4; m++) {
            size_t off = (size_t)(row0 + m * 16 + r16) * D + k0;
            ah[m] = load_bf8(Xh + off);
            al[m] = load_bf8(Xl + off);
        }
        #pragma unroll
        for (int n = 0; n < 4; n++) {
            size_t off = (size_t)(wc + n * 16 + r16) * D + k0;
            bh[n] = load_bf8(Wh + off);
            bl[n] = load_bf8(Wl + off);
        }
        #pragma unroll
        for (int m = 0; m < 4; m++)
            #pragma unroll
            for (int n = 0; n < 4; n++) {
                acc[m][n] = __builtin_amdgcn_mfma_f32_16x16x32_bf16(ah[m], bh[n], acc[m][n], 0, 0, 0);
                acc[m][n] = __builtin_amdgcn_mfma_f32_16x16x32_bf16(al[m], bh[n], acc[m][n], 0, 0, 0);
                acc[m][n] = __builtin_amdgcn_mfma_f32_16x16x32_bf16(ah[m], bl[n], acc[m][n], 0, 0, 0);
            }
    }

    // C/D layout: col = lane&15, row = (lane>>4)*4 + reg
    #pragma unroll
    for (int n = 0; n < 4; n++) {
        int col = wc + n * 16 + r16;
        float bv = bias ? bias[col] * bsc : 0.0f;
        #pragma unroll
        for (int m = 0; m < 4; m++) {
            int rbase = row0 + m * 16 + kg * 4;
            #pragma unroll
            for (int r = 0; r < 4; r++)
                O[(size_t)(rbase + r) * 256 + col] = acc[m][n][r] + bv;
        }
    }
}

// Edge gate + aggregate + FUSED per-feature stats of agg.
// Base-2 folded math (output = true agg / ln2; BN-invariant).
// 8 nodes/block, 32 lanes/node, float4/lane; graph-affine XCD swizzle;
// 2-stage gather pipeline; packed fp32 for the affine part.
__global__ __launch_bounds__(256) void k_edges(
        const int2* __restrict__ jd,
        const float* __restrict__ AfAs, const float* __restrict__ BfBs,
        const float* __restrict__ wfd, const float* __restrict__ wsd,
        float* __restrict__ agg, float* __restrict__ st1, int N, int S, int G, int deg) {
    __shared__ int2 jds[512];
    __shared__ f4 sred[256];
    __shared__ f4 sredq[256];
    int b = blockIdx.x;
    int node0;
    if ((G & 7) == 0 && (S & 7) == 0) {
        int xcd = b & 7, i = b >> 3;
        int bpg = S >> 3;                       // blocks per graph
        int gi = i / bpg, li = i - gi * bpg;
        node0 = (xcd + 8 * gi) * S + li * 8;    // graph g on XCD g%8
    } else node0 = b * 8;
    int tid = threadIdx.x;
    int grp = tid >> 5, lane = tid & 31;
    bool use_lds = (8 * deg) <= 512;
    if (use_lds) {
        int tot = 8 * deg;
        int lim = (node0 + 8 <= N) ? tot : (N > node0 ? (N - node0) * deg : 0);
        for (int t = tid; t < lim; t += 256) jds[t] = jd[(size_t)node0 * deg + t];
    }
    __syncthreads();
    int node = node0 + grp;
    bool active = node < N;
    int d0 = lane * 4;
    f4 acc = {0.f, 0.f, 0.f, 0.f};
    if (active) {
        const f4 af4 = *reinterpret_cast<const f4*>(AfAs + (size_t)node * 256 + d0);
        const f4 as4 = *reinterpret_cast<const f4*>(AfAs + (size_t)node * 256 + 128 + d0);
        const f4 wf4 = *reinterpret_cast<const f4*>(wfd + d0) * (-LOG2E);
        const f4 ws4 = *reinterpret_cast<const f4*>(wsd + d0) * (LOG2E);
        f2 af_a = {af4[0], af4[1]}, af_b = {af4[2], af4[3]};
        f2 as_a = {as4[0], as4[1]}, as_b = {as4[2], as4[3]};
        f2 wf_a = {wf4[0], wf4[1]}, wf_b = {wf4[2], wf4[3]};
        f2 ws_a = {ws4[0], ws4[1]}, ws_b = {ws4[2], ws4[3]};
        const int2* jrow = use_lds ? (jds + grp * deg) : (jd + (size_t)node * deg);
        int2 p = jrow[0];
        int off = (p.x << 8) + d0;
        f4 bf4 = *reinterpret_cast<const f4*>(BfBs + off);
        f4 bs4 = *reinterpret_cast<const f4*>(BfBs + off + 128);
        #pragma unroll 4
        for (int e = 0; e < deg; e++) {
            float dst = __int_as_float(p.y);
            f4 nbf, nbs;
            if (e + 1 < deg) {                  // prefetch next edge
                int2 np = jrow[e + 1];
                int noff = (np.x << 8) + d0;
                nbf = *reinterpret_cast<const f4*>(BfBs + noff);
                nbs = *reinterpret_cast<const f4*>(BfBs + noff + 128);
                p = np;
            }
            f2 dst2 = {dst, dst};
            f2 u_a = pk_add(pk_fma(dst2, wf_a, af_a), f2{bf4[0], bf4[1]});
            f2 u_b = pk_add(pk_fma(dst2, wf_b, af_b), f2{bf4[2], bf4[3]});
            f2 v_a = pk_add(pk_fma(dst2, ws_a, as_a), f2{bs4[0], bs4[1]});
            f2 v_b = pk_add(pk_fma(dst2, ws_b, as_b), f2{bs4[2], bs4[3]});
            float u[4] = {u_a[0], u_a[1], u_b[0], u_b[1]};
            float v[4] = {v_a[0], v_a[1], v_b[0], v_b[1]};
            #pragma unroll
            for (int c = 0; c < 4; c++) {
                float s = exp2_hw(u[c]);                      // e^{-uu}
                float t = exp2_hw(v[c]);                      // e^{vv}
                float sg = __builtin_amdgcn_rcpf(1.0f + s);   // sigmoid
                float sp = log2_hw(1.0f + t);                 // softplus/ln2
                acc[c] = fmaf(sg, sp, acc[c]);
            }
            bf4 = nbf; bs4 = nbs;
        }
        *reinterpret_cast<f4*>(agg + (size_t)node * D + d0) = acc;
    }
    // fused stats: block-reduce sum/sumsq over the 8 nodes, 8-way replicated atomics
    sred[tid] = acc;
    sredq[tid] = acc * acc;
    __syncthreads();
    if (tid < 64) {
        int which = tid >> 5, l = tid & 31;
        f4 s = which ? sredq[l] : sred[l];
        #pragma unroll
        for (int g = 1; g < 8; g++) s += which ? sredq[g * 32 + l] : sred[g * 32 + l];
        float* dstp = st1 + (b & 7) * 256 + which * 128;
        #pragma unroll
        for (int c = 0; c < 4; c++) atomicAdd(dstp + l * 4 + c, s[c]);
    }
}

// xnew = gc*(agg-mu1)*rsqrt(var1+eps)+bc+x (in place), accumulate stats of xnew.
// stats1 read from 8 replicated slots.
__global__ __launch_bounds__(256) void k_bn1res(
        const float* __restrict__ st1,
        const float* __restrict__ gc, const float* __restrict__ bc,
        const float* __restrict__ x, float* __restrict__ aggxnew,
        float* __restrict__ sums2, float* __restrict__ sumsq2, int N) {
    __shared__ f4 s1[256], s2[256];
    int tid = threadIdx.x;
    int sl = tid & 31, grp = tid >> 5;
    int d0 = sl * 4;
    float invN = 1.0f / (float)N;
    f4 mu = {0.f, 0.f, 0.f, 0.f}, sq = {0.f, 0.f, 0.f, 0.f};
    #pragma unroll
    for (int r = 0; r < 8; r++) {
        mu += *reinterpret_cast<const f4*>(st1 + r * 256 + d0);
        sq += *reinterpret_cast<const f4*>(st1 + r * 256 + 128 + d0);
    }
    f4 g4 = *reinterpret_cast<const f4*>(gc + d0);
    f4 b4 = *reinterpret_cast<const f4*>(bc + d0);
    f4 inv;
    #pragma unroll
    for (int c = 0; c < 4; c++) {
        float m = mu[c] * invN;
        mu[c] = m;
        inv[c] = rsqrtf(sq[c] * invN - m * m + 1e-5f);
    }
    f4 sa = {0.f, 0.f, 0.f, 0.f}, sb = {0.f, 0.f, 0.f, 0.f};
    for (int r = blockIdx.x * 8 + grp; r < N; r += gridDim.x * 8) {
        size_t idx = (size_t)r * D + d0;
        f4 v = *reinterpret_cast<const f4*>(aggxnew + idx);
        f4 xv = *reinterpret_cast<const f4*>(x + idx);
        f4 xn;
        #pragma unroll
        for (int c = 0; c < 4; c++) xn[c] = fmaf(g4[c] * (v[c] - mu[c]), inv[c], b4[c]) + xv[c];
        *reinterpret_cast<f4*>(aggxnew + idx) = xn;
        sa += xn;
        sb += xn * xn;
    }
    s1[tid] = sa;
    s2[tid] = sb;
    __syncthreads();
    if (tid < 64) {
        int which = tid >> 5, l = tid & 31;
        f4 acc = which ? s2[l] : s1[l];
        #pragma unroll
        for (int g = 1; g < 8; g++) acc += which ? s2[g * 32 + l] : s1[g * 32 + l];
        float* dstp = which ? sumsq2 : sums2;
        #pragma unroll
        for (int c = 0; c < 4; c++) atomicAdd(dstp + l * 4 + c, acc[c]);
    }
}

// x = relu(gn*(xnew-mu2)*rsqrt(var2+eps)+bnb); emit bf16 hi/lo. float4 per thread.
__global__ __launch_bounds__(256) void k_bn2relu(
        const float* __restrict__ sums2, const float* __restrict__ sumsq2,
        const float* __restrict__ gn, const float* __restrict__ bnb,
        const float* __restrict__ xnew, float* __restrict__ xout,
        unsigned short* __restrict__ xh, unsigned short* __restrict__ xl, int N) {
    int idx = blockIdx.x * blockDim.x + threadIdx.x;      // N*32 threads
    if (idx >= N * 32) return;
    int n = idx >> 5;
    int d0 = (idx & 31) * 4;
    float invN = 1.0f / (float)N;
    f4 mu = *reinterpret_cast<const f4*>(sums2 + d0);
    f4 sq = *reinterpret_cast<const f4*>(sumsq2 + d0);
    f4 g4 = *reinterpret_cast<const f4*>(gn + d0);
    f4 b4 = *reinterpret_cast<const f4*>(bnb + d0);
    f4 v = *reinterpret_cast<const f4*>(xnew + (size_t)n * D + d0);
    f4 o;
    u16x4 h, l;
    #pragma unroll
    for (int c = 0; c < 4; c++) {
        float m = mu[c] * invN;
        float inv = rsqrtf(sq[c] * invN - m * m + 1e-5f);
        float t = fmaf(g4[c] * (v[c] - m), inv, b4[c]);
        t = fmaxf(t, 0.0f);
        o[c] = t;
        h[c] = f2bf(t);
        l[c] = f2bf(t - bf2f(h[c]));
    }
    *reinterpret_cast<f4*>(xout + (size_t)n * D + d0) = o;
    *reinterpret_cast<u16x4*>(xh + (size_t)n * D + d0) = h;
    *reinterpret_cast<u16x4*>(xl + (size_t)n * D + d0) = l;
}

// Per-graph feature sums: 8 blocks per graph, atomicAdd into gsum[G][D] (pre-zeroed)
__global__ __launch_bounds__(256) void k_pool(const float* __restrict__ x,
        float* __restrict__ gsum, int S) {
    __shared__ f4 s[256];
    int b = blockIdx.x;
    int g = b >> 3, sub = b & 7;
    int tid = threadIdx.x;
    int grp = tid >> 5, lane = tid & 31;
    int d0 = lane * 4;
    f4 a = {0.f, 0.f, 0.f, 0.f};
    for (int r = sub * 8 + grp; r < S; r += 64)
        a += *reinterpret_cast<const f4*>(x + ((size_t)g * S + r) * D + d0);
    s[tid] = a;
    __syncthreads();
    if (tid < 32) {
        f4 acc = s[tid];
        #pragma unroll
        for (int q = 1; q < 8; q++) acc += s[q * 32 + tid];
        #pragma unroll
        for (int c = 0; c < 4; c++) atomicAdd(&gsum[g * D + tid * 4 + c], acc[c]);
    }
}

// out[g] = relu(gmean@W1+b1) @ W2 + b2
__global__ __launch_bounds__(128) void k_mlp(const float* __restrict__ gsum,
        const float* __restrict__ W1, const float* __restrict__ b1,
        const float* __restrict__ W2, const float* __restrict__ b2,
        float* __restrict__ out, int S) {
    __shared__ float gm[D];
    __shared__ float red[128];
    int g = blockIdx.x, d = threadIdx.x;
    gm[d] = gsum[g * D + d] / (float)S;
    __syncthreads();
    float h = b1[d];
    #pragma unroll 8
    for (int k = 0; k < D; k++) h = fmaf(gm[k], W1[k * D + d], h);
    h = fmaxf(h, 0.0f);
    red[d] = h * W2[d];
    __syncthreads();
    for (int st = 64; st > 0; st >>= 1) {
        if (d < st) red[d] += red[d + st];
        __syncthreads();
    }
    if (d == 0) out[g] = red[0] + b2[0];
}

extern "C" void kernel_launch(void* const* d_in, const int* in_sizes, int n_in,
                              void* d_out, int out_size, void* d_ws, size_t ws_size,
                              hipStream_t stream) {
    const int*   z    = (const int*)d_in[0];
    const float* pos  = (const float*)d_in[1];
    const int*   eidx = (const int*)d_in[3];
    const float* emb  = (const float*)d_in[4];
    const float* Wf   = (const float*)d_in[5];
    const float* bf   = (const float*)d_in[6];
    const float* Ws   = (const float*)d_in[7];
    const float* bs   = (const float*)d_in[8];
    const float* gc   = (const float*)d_in[9];
    const float* bc   = (const float*)d_in[10];
    const float* gn   = (const float*)d_in[11];
    const float* bnb  = (const float*)d_in[12];
    const float* W1   = (const float*)d_in[13];
    const float* b1   = (const float*)d_in[14];
    const float* W2   = (const float*)d_in[15];
    const float* b2   = (const float*)d_in[16];

    int N = in_sizes[0];
    int E = in_sizes[3] / 2;
    int L = in_sizes[6] / D;
    int deg = E / N;
    int G = out_size;
    int S = N / G;

    const int* row = eidx;
    const int* col = eidx + E;

    float* ws = (float*)d_ws;
    size_t nd = (size_t)N * D;
    float* x    = ws;                  // [N][128]
    float* AfAs = x + nd;              // [N][256]
    float* BfBs = AfAs + 2 * nd;       // [N][256]
    float* agg  = BfBs + 2 * nd;       // [N][128], reused as xnew in place
    int2*  jd   = (int2*)(agg + nd);   // [E] packed (j, dist)
    unsigned short* xh  = (unsigned short*)(jd + E);
    unsigned short* xl  = xh + nd;
    unsigned short* Wth = xl + nd;                          // L*4*128*128 bf16
    unsigned short* Wtl = Wth + (size_t)L * 4 * D * D;
    float* stats = (float*)(Wtl + (size_t)L * 4 * D * D);
    // per layer: [0..2047] st1 replicated 8x(sum128|sq128), [2048..2175] sums2, [2176..2303] sumsq2
    float* gsum  = stats + (size_t)L * 2304;                // G*128 floats

    hipMemsetAsync(stats, 0, ((size_t)L * 2304 + (size_t)G * D) * sizeof(float), stream);

    k_cvtW<<<(L * 4 * D * D + 255) / 256, 256, 0, stream>>>(Wf, Ws, Wth, Wtl, L);
    k_embed<<<(N * 32 + 255) / 256, 256, 0, stream>>>(z, emb, x, xh, xl, N);
    k_dist<<<(E + 255) / 256, 256, 0, stream>>>(row, col, pos, jd, E);

    for (int l = 0; l < L; ++l) {
        const float* Wfl = Wf + (size_t)l * 257 * D;
        const float* Wsl = Ws + (size_t)l * 257 * D;
        float* st = stats + (size_t)l * 2304;
        k_gemm_mfma<<<dim3(N / 128, 4), 256, 0, stream>>>(
            xh, xl, Wth + (size_t)l * 4 * D * D, Wtl + (size_t)l * 4 * D * D,
            bf + l * D, bs + l * D, AfAs, BfBs, S, G);
        k_edges<<<(N + 7) / 8, 256, 0, stream>>>(jd, AfAs, BfBs,
                                                 Wfl + 256 * D, Wsl + 256 * D, agg, st, N, S, G, deg);
        k_bn1res<<<256, 256, 0, stream>>>(st, gc + l * D, bc + l * D,
                                          x, agg, st + 2048, st + 2176, N);
        k_bn2relu<<<(N * 32 + 255) / 256, 256, 0, stream>>>(st + 2048, st + 2176,
                                                            gn + l * D, bnb + l * D, agg, x, xh, xl, N);
    }
    k_pool<<<G * 8, 256, 0, stream>>>(x, gsum, S);
    k_mlp<<<G, 128, 0, stream>>>(gsum, W1, b1, W2, b2, (float*)d_out, S);
}

// Round 7
// 641.594 us; speedup vs baseline: 1.6580x; 1.0148x over previous
//
#include <hip/hip_runtime.h>
#include <math.h>

#define D 128
#define LOG2E 1.44269504f

typedef short bf16x8 __attribute__((ext_vector_type(8)));
typedef float f32x4 __attribute__((ext_vector_type(4)));
typedef float f4 __attribute__((ext_vector_type(4)));
typedef unsigned short u16x4 __attribute__((ext_vector_type(4)));

__device__ __forceinline__ unsigned short f2bf(float f) {
    unsigned int u = __float_as_uint(f);
    u += 0x7fff + ((u >> 16) & 1);   // round-to-nearest-even
    return (unsigned short)(u >> 16);
}
__device__ __forceinline__ float bf2f(unsigned short h) {
    return __uint_as_float(((unsigned int)h) << 16);
}
__device__ __forceinline__ bf16x8 load_bf8(const unsigned short* p) {
    return __builtin_bit_cast(bf16x8, *reinterpret_cast<const uint4*>(p));
}
// raw HW transcendentals (v_exp_f32 = 2^x, v_log_f32 = log2)
__device__ __forceinline__ float exp2_hw(float x) {
    float r; asm("v_exp_f32 %0, %1" : "=v"(r) : "v"(x)); return r;
}
__device__ __forceinline__ float log2_hw(float x) {
    float r; asm("v_log_f32 %0, %1" : "=v"(r) : "v"(x)); return r;
}

// x[n][d] = emb[z[n]][d]; also emit bf16 hi/lo split. float4 per thread.
__global__ __launch_bounds__(256) void k_embed(const int* __restrict__ z,
        const float* __restrict__ emb, float* __restrict__ x,
        unsigned short* __restrict__ xh, unsigned short* __restrict__ xl, int N) {
    int idx = blockIdx.x * blockDim.x + threadIdx.x;       // N*32 threads
    if (idx >= N * 32) return;
    int n = idx >> 5;
    int d0 = (idx & 31) * 4;
    f4 v = *reinterpret_cast<const f4*>(emb + (size_t)z[n] * D + d0);
    *reinterpret_cast<f4*>(x + (size_t)n * D + d0) = v;
    u16x4 h, l;
    #pragma unroll
    for (int c = 0; c < 4; c++) {
        h[c] = f2bf(v[c]);
        l[c] = f2bf(v[c] - bf2f(h[c]));
    }
    *reinterpret_cast<u16x4*>(xh + (size_t)n * D + d0) = h;
    *reinterpret_cast<u16x4*>(xl + (size_t)n * D + d0) = l;
}

// jd[e] = (row[e], bits(||pos[row]-pos[col]||)) packed
__global__ void k_dist(const int* __restrict__ row, const int* __restrict__ col,
                       const float* __restrict__ pos, int2* __restrict__ jd, int E) {
    int e = blockIdx.x * blockDim.x + threadIdx.x;
    if (e >= E) return;
    int r = row[e], c = col[e];
    float dx = pos[3 * r + 0] - pos[3 * c + 0];
    float dy = pos[3 * r + 1] - pos[3 * c + 1];
    float dz = pos[3 * r + 2] - pos[3 * c + 2];
    float dist = sqrtf(dx * dx + dy * dy + dz * dz);
    jd[e] = make_int2(r, __float_as_int(dist));
}

// Pre-transpose + bf16 hi/lo split all layer weights, PRE-SCALED for base-2 gate:
// f-path (mats 0,1) x (-log2e), s-path (mats 2,3) x (+log2e).
__global__ void k_cvtW(const float* __restrict__ Wf, const float* __restrict__ Ws,
                       unsigned short* __restrict__ Wth, unsigned short* __restrict__ Wtl,
                       int L) {
    int idx = blockIdx.x * blockDim.x + threadIdx.x;
    if (idx >= L * 4 * D * D) return;
    int k = idx & 127;
    int n = (idx >> 7) & 127;
    int mat = (idx >> 14) & 3;
    int l = idx >> 16;
    const float* src = (mat < 2) ? Wf : Ws;
    float scale = (mat < 2) ? -LOG2E : LOG2E;
    float v = scale * src[(size_t)l * 257 * D + (size_t)((mat & 1) * D + k) * D + n];
    unsigned short h = f2bf(v);
    Wth[idx] = h;
    Wtl[idx] = f2bf(v - bf2f(h));
}

// Split-bf16 MFMA GEMM (2-term: Xh*Wh + Xl*Wh), graph-affine XCD swizzle.
// Outputs interleaved: AfAs[N][256] = [Af|As], BfBs[N][256] = [Bf|Bs]  (pre-scaled)
__global__ __launch_bounds__(256) void k_gemm_mfma(
        const unsigned short* __restrict__ Xh, const unsigned short* __restrict__ Xl,
        const unsigned short* __restrict__ Wth, const unsigned short* __restrict__ Wtl,
        const float* __restrict__ bfl, const float* __restrict__ bsl,
        float* __restrict__ AfAs, float* __restrict__ BfBs, int S, int G) {
    int mat = blockIdx.y;                      // 0=Af 1=Bf 2=As 3=Bs
    float* O = ((mat & 1) ? BfBs : AfAs) + ((mat >> 1) ? 128 : 0);
    const float* bias = (mat == 0) ? bfl : (mat == 2) ? bsl : nullptr;
    float bsc = (mat == 0) ? -LOG2E : LOG2E;
    const unsigned short* Wh = Wth + (size_t)mat * D * D;

    int wave = threadIdx.x >> 6;
    int lane = threadIdx.x & 63;
    int r16 = lane & 15;
    int kg = lane >> 4;

    int xb = blockIdx.x;
    int tile0;
    if ((G & 7) == 0 && (S & 127) == 0) {
        int xcd = xb & 7, i = xb >> 3;
        int tpg = S >> 7;                       // 128-row tiles per graph
        int gi = i / tpg, t = i - gi * tpg;
        tile0 = (xcd + 8 * gi) * S + t * 128;   // graph g on XCD g%8
    } else tile0 = xb * 128;
    int row0 = tile0 + (wave >> 1) * 64;
    int wc = (wave & 1) * 64;

    f32x4 acc[4][4];
    #pragma unroll
    for (int m = 0; m < 4; m++)
        #pragma unroll
        for (int n = 0; n < 4; n++) acc[m][n] = (f32x4){0.f, 0.f, 0.f, 0.f};

    #pragma unroll
    for (int ks = 0; ks < 4; ++ks) {
        int k0 = ks * 32 + kg * 8;
        bf16x8 ah[4], al[4], bh[4];
        #pragma unroll
        for (int m = 0; m < 4; m++) {
            size_t off = (size_t)(row0 + m * 16 + r16) * D + k0;
            ah[m] = load_bf8(Xh + off);
            al[m] = load_bf8(Xl + off);
        }
        #pragma unroll
        for (int n = 0; n < 4; n++) {
            size_t off = (size_t)(wc + n * 16 + r16) * D + k0;
            bh[n] = load_bf8(Wh + off);
        }
        #pragma unroll
        for (int m = 0; m < 4; m++)
            #pragma unroll
            for (int n = 0; n < 4; n++) {
                acc[m][n] = __builtin_amdgcn_mfma_f32_16x16x32_bf16(ah[m], bh[n], acc[m][n], 0, 0, 0);
                acc[m][n] = __builtin_amdgcn_mfma_f32_16x16x32_bf16(al[m], bh[n], acc[m][n], 0, 0, 0);
            }
    }

    // C/D layout: col = lane&15, row = (lane>>4)*4 + reg
    #pragma unroll
    for (int n = 0; n < 4; n++) {
        int col = wc + n * 16 + r16;
        float bv = bias ? bias[col] * bsc : 0.0f;
        #pragma unroll
        for (int m = 0; m < 4; m++) {
            int rbase = row0 + m * 16 + kg * 4;
            #pragma unroll
            for (int r = 0; r < 4; r++)
                O[(size_t)(rbase + r) * 256 + col] = acc[m][n][r] + bv;
        }
    }
}

// Edge gate + aggregate + FUSED per-feature stats of agg.
// Base-2 folded math (output = true agg / ln2; BN-invariant).
// 8 nodes/block, 32 lanes/node, float4/lane; graph-affine XCD swizzle.
// Inner loop: simple branchless form (R4) — compiler schedules the gather.
__global__ __launch_bounds__(256) void k_edges(
        const int2* __restrict__ jd,
        const float* __restrict__ AfAs, const float* __restrict__ BfBs,
        const float* __restrict__ wfd, const float* __restrict__ wsd,
        float* __restrict__ agg, float* __restrict__ st1, int N, int S, int G, int deg) {
    __shared__ int2 jds[512];
    __shared__ f4 sred[256];
    __shared__ f4 sredq[256];
    int b = blockIdx.x;
    int node0;
    if ((G & 7) == 0 && (S & 7) == 0) {
        int xcd = b & 7, i = b >> 3;
        int bpg = S >> 3;                       // blocks per graph
        int gi = i / bpg, li = i - gi * bpg;
        node0 = (xcd + 8 * gi) * S + li * 8;    // graph g on XCD g%8
    } else node0 = b * 8;
    int tid = threadIdx.x;
    int grp = tid >> 5, lane = tid & 31;
    bool use_lds = (8 * deg) <= 512;
    if (use_lds) {
        int tot = 8 * deg;
        int lim = (node0 + 8 <= N) ? tot : (N > node0 ? (N - node0) * deg : 0);
        for (int t = tid; t < lim; t += 256) jds[t] = jd[(size_t)node0 * deg + t];
    }
    __syncthreads();
    int node = node0 + grp;
    bool active = node < N;
    int d0 = lane * 4;
    f4 acc = {0.f, 0.f, 0.f, 0.f};
    if (active) {
        const f4 af4 = *reinterpret_cast<const f4*>(AfAs + (size_t)node * 256 + d0);
        const f4 as4 = *reinterpret_cast<const f4*>(AfAs + (size_t)node * 256 + 128 + d0);
        const f4 wf4 = *reinterpret_cast<const f4*>(wfd + d0) * (-LOG2E);
        const f4 ws4 = *reinterpret_cast<const f4*>(wsd + d0) * (LOG2E);
        const int2* jrow = use_lds ? (jds + grp * deg) : (jd + (size_t)node * deg);
        #pragma unroll 8
        for (int e = 0; e < deg; e++) {
            int2 p = jrow[e];
            float dst = __int_as_float(p.y);
            int off = (p.x << 8) + d0;          // 32-bit offset
            f4 bf4 = *reinterpret_cast<const f4*>(BfBs + off);
            f4 bs4 = *reinterpret_cast<const f4*>(BfBs + off + 128);
            #pragma unroll
            for (int c = 0; c < 4; c++) {
                float u2 = fmaf(dst, wf4[c], af4[c]) + bf4[c];   // = -log2e * u
                float v2 = fmaf(dst, ws4[c], as4[c]) + bs4[c];   // = +log2e * v
                float s = exp2_hw(u2);                            // e^{-u}
                float t = exp2_hw(v2);                            // e^{v}
                float sg = __builtin_amdgcn_rcpf(1.0f + s);       // sigmoid(u)
                float sp = log2_hw(1.0f + t);                     // softplus(v)/ln2
                acc[c] = fmaf(sg, sp, acc[c]);
            }
        }
        *reinterpret_cast<f4*>(agg + (size_t)node * D + d0) = acc;
    }
    // fused stats: block-reduce sum/sumsq over the 8 nodes, 8-way replicated atomics
    sred[tid] = acc;
    sredq[tid] = acc * acc;
    __syncthreads();
    if (tid < 64) {
        int which = tid >> 5, l = tid & 31;
        f4 s = which ? sredq[l] : sred[l];
        #pragma unroll
        for (int g = 1; g < 8; g++) s += which ? sredq[g * 32 + l] : sred[g * 32 + l];
        float* dstp = st1 + (b & 7) * 256 + which * 128;
        #pragma unroll
        for (int c = 0; c < 4; c++) atomicAdd(dstp + l * 4 + c, s[c]);
    }
}

// xnew = gc*(agg-mu1)*rsqrt(var1+eps)+bc+x (in place), accumulate stats of xnew.
// stats1 read from 8 replicated slots.
__global__ __launch_bounds__(256) void k_bn1res(
        const float* __restrict__ st1,
        const float* __restrict__ gc, const float* __restrict__ bc,
        const float* __restrict__ x, float* __restrict__ aggxnew,
        float* __restrict__ sums2, float* __restrict__ sumsq2, int N) {
    __shared__ f4 s1[256], s2[256];
    int tid = threadIdx.x;
    int sl = tid & 31, grp = tid >> 5;
    int d0 = sl * 4;
    float invN = 1.0f / (float)N;
    f4 mu = {0.f, 0.f, 0.f, 0.f}, sq = {0.f, 0.f, 0.f, 0.f};
    #pragma unroll
    for (int r = 0; r < 8; r++) {
        mu += *reinterpret_cast<const f4*>(st1 + r * 256 + d0);
        sq += *reinterpret_cast<const f4*>(st1 + r * 256 + 128 + d0);
    }
    f4 g4 = *reinterpret_cast<const f4*>(gc + d0);
    f4 b4 = *reinterpret_cast<const f4*>(bc + d0);
    f4 inv;
    #pragma unroll
    for (int c = 0; c < 4; c++) {
        float m = mu[c] * invN;
        mu[c] = m;
        inv[c] = rsqrtf(sq[c] * invN - m * m + 1e-5f);
    }
    f4 sa = {0.f, 0.f, 0.f, 0.f}, sb = {0.f, 0.f, 0.f, 0.f};
    for (int r = blockIdx.x * 8 + grp; r < N; r += gridDim.x * 8) {
        size_t idx = (size_t)r * D + d0;
        f4 v = *reinterpret_cast<const f4*>(aggxnew + idx);
        f4 xv = *reinterpret_cast<const f4*>(x + idx);
        f4 xn;
        #pragma unroll
        for (int c = 0; c < 4; c++) xn[c] = fmaf(g4[c] * (v[c] - mu[c]), inv[c], b4[c]) + xv[c];
        *reinterpret_cast<f4*>(aggxnew + idx) = xn;
        sa += xn;
        sb += xn * xn;
    }
    s1[tid] = sa;
    s2[tid] = sb;
    __syncthreads();
    if (tid < 64) {
        int which = tid >> 5, l = tid & 31;
        f4 acc = which ? s2[l] : s1[l];
        #pragma unroll
        for (int g = 1; g < 8; g++) acc += which ? s2[g * 32 + l] : s1[g * 32 + l];
        float* dstp = which ? sumsq2 : sums2;
        #pragma unroll
        for (int c = 0; c < 4; c++) atomicAdd(dstp + l * 4 + c, acc[c]);
    }
}

// x = relu(gn*(xnew-mu2)*rsqrt(var2+eps)+bnb); emit bf16 hi/lo. float4 per thread.
__global__ __launch_bounds__(256) void k_bn2relu(
        const float* __restrict__ sums2, const float* __restrict__ sumsq2,
        const float* __restrict__ gn, const float* __restrict__ bnb,
        const float* __restrict__ xnew, float* __restrict__ xout,
        unsigned short* __restrict__ xh, unsigned short* __restrict__ xl, int N) {
    int idx = blockIdx.x * blockDim.x + threadIdx.x;      // N*32 threads
    if (idx >= N * 32) return;
    int n = idx >> 5;
    int d0 = (idx & 31) * 4;
    float invN = 1.0f / (float)N;
    f4 mu = *reinterpret_cast<const f4*>(sums2 + d0);
    f4 sq = *reinterpret_cast<const f4*>(sumsq2 + d0);
    f4 g4 = *reinterpret_cast<const f4*>(gn + d0);
    f4 b4 = *reinterpret_cast<const f4*>(bnb + d0);
    f4 v = *reinterpret_cast<const f4*>(xnew + (size_t)n * D + d0);
    f4 o;
    u16x4 h, l;
    #pragma unroll
    for (int c = 0; c < 4; c++) {
        float m = mu[c] * invN;
        float inv = rsqrtf(sq[c] * invN - m * m + 1e-5f);
        float t = fmaf(g4[c] * (v[c] - m), inv, b4[c]);
        t = fmaxf(t, 0.0f);
        o[c] = t;
        h[c] = f2bf(t);
        l[c] = f2bf(t - bf2f(h[c]));
    }
    *reinterpret_cast<f4*>(xout + (size_t)n * D + d0) = o;
    *reinterpret_cast<u16x4*>(xh + (size_t)n * D + d0) = h;
    *reinterpret_cast<u16x4*>(xl + (size_t)n * D + d0) = l;
}

// Per-graph feature sums: 8 blocks per graph, atomicAdd into gsum[G][D] (pre-zeroed)
__global__ __launch_bounds__(256) void k_pool(const float* __restrict__ x,
        float* __restrict__ gsum, int S) {
    __shared__ f4 s[256];
    int b = blockIdx.x;
    int g = b >> 3, sub = b & 7;
    int tid = threadIdx.x;
    int grp = tid >> 5, lane = tid & 31;
    int d0 = lane * 4;
    f4 a = {0.f, 0.f, 0.f, 0.f};
    for (int r = sub * 8 + grp; r < S; r += 64)
        a += *reinterpret_cast<const f4*>(x + ((size_t)g * S + r) * D + d0);
    s[tid] = a;
    __syncthreads();
    if (tid < 32) {
        f4 acc = s[tid];
        #pragma unroll
        for (int q = 1; q < 8; q++) acc += s[q * 32 + tid];
        #pragma unroll
        for (int c = 0; c < 4; c++) atomicAdd(&gsum[g * D + tid * 4 + c], acc[c]);
    }
}

// out[g] = relu(gmean@W1+b1) @ W2 + b2
__global__ __launch_bounds__(128) void k_mlp(const float* __restrict__ gsum,
        const float* __restrict__ W1, const float* __restrict__ b1,
        const float* __restrict__ W2, const float* __restrict__ b2,
        float* __restrict__ out, int S) {
    __shared__ float gm[D];
    __shared__ float red[128];
    int g = blockIdx.x, d = threadIdx.x;
    gm[d] = gsum[g * D + d] / (float)S;
    __syncthreads();
    float h = b1[d];
    #pragma unroll 8
    for (int k = 0; k < D; k++) h = fmaf(gm[k], W1[k * D + d], h);
    h = fmaxf(h, 0.0f);
    red[d] = h * W2[d];
    __syncthreads();
    for (int st = 64; st > 0; st >>= 1) {
        if (d < st) red[d] += red[d + st];
        __syncthreads();
    }
    if (d == 0) out[g] = red[0] + b2[0];
}

extern "C" void kernel_launch(void* const* d_in, const int* in_sizes, int n_in,
                              void* d_out, int out_size, void* d_ws, size_t ws_size,
                              hipStream_t stream) {
    const int*   z    = (const int*)d_in[0];
    const float* pos  = (const float*)d_in[1];
    const int*   eidx = (const int*)d_in[3];
    const float* emb  = (const float*)d_in[4];
    const float* Wf   = (const float*)d_in[5];
    const float* bf   = (const float*)d_in[6];
    const float* Ws   = (const float*)d_in[7];
    const float* bs   = (const float*)d_in[8];
    const float* gc   = (const float*)d_in[9];
    const float* bc   = (const float*)d_in[10];
    const float* gn   = (const float*)d_in[11];
    const float* bnb  = (const float*)d_in[12];
    const float* W1   = (const float*)d_in[13];
    const float* b1   = (const float*)d_in[14];
    const float* W2   = (const float*)d_in[15];
    const float* b2   = (const float*)d_in[16];

    int N = in_sizes[0];
    int E = in_sizes[3] / 2;
    int L = in_sizes[6] / D;
    int deg = E / N;
    int G = out_size;
    int S = N / G;

    const int* row = eidx;
    const int* col = eidx + E;

    float* ws = (float*)d_ws;
    size_t nd = (size_t)N * D;
    float* x    = ws;                  // [N][128]
    float* AfAs = x + nd;              // [N][256]
    float* BfBs = AfAs + 2 * nd;       // [N][256]
    float* agg  = BfBs + 2 * nd;       // [N][128], reused as xnew in place
    int2*  jd   = (int2*)(agg + nd);   // [E] packed (j, dist)
    unsigned short* xh  = (unsigned short*)(jd + E);
    unsigned short* xl  = xh + nd;
    unsigned short* Wth = xl + nd;                          // L*4*128*128 bf16
    unsigned short* Wtl = Wth + (size_t)L * 4 * D * D;
    float* stats = (float*)(Wtl + (size_t)L * 4 * D * D);
    // per layer: [0..2047] st1 replicated 8x(sum128|sq128), [2048..2175] sums2, [2176..2303] sumsq2
    float* gsum  = stats + (size_t)L * 2304;                // G*128 floats

    hipMemsetAsync(stats, 0, ((size_t)L * 2304 + (size_t)G * D) * sizeof(float), stream);

    k_cvtW<<<(L * 4 * D * D + 255) / 256, 256, 0, stream>>>(Wf, Ws, Wth, Wtl, L);
    k_embed<<<(N * 32 + 255) / 256, 256, 0, stream>>>(z, emb, x, xh, xl, N);
    k_dist<<<(E + 255) / 256, 256, 0, stream>>>(row, col, pos, jd, E);

    for (int l = 0; l < L; ++l) {
        const float* Wfl = Wf + (size_t)l * 257 * D;
        const float* Wsl = Ws + (size_t)l * 257 * D;
        float* st = stats + (size_t)l * 2304;
        k_gemm_mfma<<<dim3(N / 128, 4), 256, 0, stream>>>(
            xh, xl, Wth + (size_t)l * 4 * D * D, Wtl + (size_t)l * 4 * D * D,
            bf + l * D, bs + l * D, AfAs, BfBs, S, G);
        k_edges<<<(N + 7) / 8, 256, 0, stream>>>(jd, AfAs, BfBs,
                                                 Wfl + 256 * D, Wsl + 256 * D, agg, st, N, S, G, deg);
        k_bn1res<<<256, 256, 0, stream>>>(st, gc + l * D, bc + l * D,
                                          x, agg, st + 2048, st + 2176, N);
        k_bn2relu<<<(N * 32 + 255) / 256, 256, 0, stream>>>(st + 2048, st + 2176,
                                                            gn + l * D, bnb + l * D, agg, x, xh, xl, N);
    }
    k_pool<<<G * 8, 256, 0, stream>>>(x, gsum, S);
    k_mlp<<<G, 128, 0, stream>>>(gsum, W1, b1, W2, b2, (float*)d_out, S);
}